// Round 2
// baseline (2499.059 us; speedup 1.0000x reference)
//
#include <hip/hip_runtime.h>

#define CDIV(a,b) (((a)+(b)-1)/(b))

// ---------------- histogram of dst (in-degree, without self loop) ----------------
__global__ void k_hist(const int* __restrict__ dst, int E, int* __restrict__ hist) {
    int e = blockIdx.x * 256 + threadIdx.x;
    if (e < E) atomicAdd(&hist[dst[e]], 1);
}

// ---------------- 2-level exclusive scan (tiles of 256) ----------------
__global__ void k_scan_tile(const int* __restrict__ in, int N,
                            int* __restrict__ out, int* __restrict__ tilesums) {
    __shared__ int sm[256];
    int t = threadIdx.x;
    int g = blockIdx.x * 256 + t;
    int v = (g < N) ? in[g] : 0;
    sm[t] = v;
    __syncthreads();
    for (int off = 1; off < 256; off <<= 1) {
        int x = sm[t];
        int y = (t >= off) ? sm[t - off] : 0;
        __syncthreads();
        sm[t] = x + y;
        __syncthreads();
    }
    int incl = sm[t];
    if (g < N) out[g] = incl - v;           // exclusive within tile
    if (t == 255) tilesums[blockIdx.x] = incl;
}

__global__ void k_scan_sums(int* __restrict__ sums, int B) {
    __shared__ int sm[512];
    int t = threadIdx.x;
    int v = (t < B) ? sums[t] : 0;
    sm[t] = v;
    __syncthreads();
    for (int off = 1; off < 512; off <<= 1) {
        int x = sm[t];
        int y = (t >= off) ? sm[t - off] : 0;
        __syncthreads();
        sm[t] = x + y;
        __syncthreads();
    }
    if (t < B) sums[t] = sm[t] - v;         // exclusive tile offsets
}

__global__ void k_scan_add(int* __restrict__ rowst, int N,
                           const int* __restrict__ sums, int* __restrict__ cursor) {
    int g = blockIdx.x * 256 + threadIdx.x;
    if (g < N) {
        int v = rowst[g] + sums[blockIdx.x];
        rowst[g] = v;
        cursor[g] = v;
    }
}

// ---------------- per-node: inv_sqrt(deg) and xi = x*inv ----------------
__global__ void k_inv(const int* __restrict__ hist, const float* __restrict__ x, int N,
                      float* __restrict__ inv, float* __restrict__ xi) {
    int i = blockIdx.x * 256 + threadIdx.x;
    if (i < N) {
        float iv = rsqrtf((float)(hist[i] + 1));   // +1 self loop
        inv[i] = iv;
        xi[i]  = x[i] * iv;
    }
}

// ---------------- scatter edges into CSR buckets ----------------
__global__ void k_scatter(const int* __restrict__ src, const int* __restrict__ dst, int E,
                          int* __restrict__ cursor, int* __restrict__ sorted) {
    int e = blockIdx.x * 256 + threadIdx.x;
    if (e < E) {
        int p = atomicAdd(&cursor[dst[e]], 1);
        sorted[p] = src[e];
    }
}

// ---------------- layer-1 scalar aggregation: si[d] = (s[d], inv[d]) ----------------
__global__ void k_s(const int* __restrict__ sorted, const int* __restrict__ rowst,
                    const int* __restrict__ cnt, const float* __restrict__ xi,
                    const float* __restrict__ inv, int N, float2* __restrict__ si) {
    int i = blockIdx.x * 256 + threadIdx.x;
    if (i < N) {
        int st = rowst[i], en = st + cnt[i];
        float acc = xi[i];                    // self-loop term
        int e = st;
        for (; e + 4 <= en; e += 4) {
            int n0 = sorted[e], n1 = sorted[e+1], n2 = sorted[e+2], n3 = sorted[e+3];
            float x0 = xi[n0], x1 = xi[n1], x2 = xi[n2], x3 = xi[n3];
            acc += (x0 + x1) + (x2 + x3);
        }
        for (; e < en; ++e) acc += xi[sorted[e]];
        float iv = inv[i];
        si[i] = make_float2(iv * acc, iv);
    }
}

// ---------------- layer-2 aggregation (pull, CSR): agg2[d,j] ----------------
// agg2[d,j] = inv[d]*( sum_{e->d} inv[src]*relu(s[src]*W1[j]+b1[j]) + inv[d]*relu(s[d]*W1[j]+b1[j]) )
__global__ __launch_bounds__(256) void k_agg2(
        const int* __restrict__ sorted, const int* __restrict__ rowst,
        const int* __restrict__ cnt, const float2* __restrict__ si,
        const float* __restrict__ W1, const float* __restrict__ b1,
        int N, float* __restrict__ agg2) {
    int j   = threadIdx.x & 127;
    int grp = threadIdx.x >> 7;               // 2 groups of 128 per block
    float w  = W1[j];
    float bb = b1[j];
    int stride = gridDim.x * 2;
    for (int d = blockIdx.x * 2 + grp; d < N; d += stride) {
        int st = rowst[d], en = st + cnt[d];
        float acc = 0.f;
        int e = st;
        for (; e + 4 <= en; e += 4) {
            int n0 = sorted[e], n1 = sorted[e+1], n2 = sorted[e+2], n3 = sorted[e+3];
            float2 p0 = si[n0];
            float2 p1 = si[n1];
            float2 p2 = si[n2];
            float2 p3 = si[n3];
            acc = fmaf(p0.y, fmaxf(fmaf(p0.x, w, bb), 0.f), acc);
            acc = fmaf(p1.y, fmaxf(fmaf(p1.x, w, bb), 0.f), acc);
            acc = fmaf(p2.y, fmaxf(fmaf(p2.x, w, bb), 0.f), acc);
            acc = fmaf(p3.y, fmaxf(fmaf(p3.x, w, bb), 0.f), acc);
        }
        for (; e < en; ++e) {
            float2 p = si[sorted[e]];
            acc = fmaf(p.y, fmaxf(fmaf(p.x, w, bb), 0.f), acc);
        }
        float2 ps = si[d];
        float oself = fmaxf(fmaf(ps.x, w, bb), 0.f);
        agg2[d * 128 + j] = ps.y * (acc + ps.y * oself);
    }
}

// ---------------- matmul + bias + relu + global-add-pool ----------------
// pool[j] += sum_d relu( agg2[d,:] @ W2[:,j] + b2[j] )
// 256 threads = 32 j-groups (4 j each, float4) x 8 row-groups (4 rows each).
__global__ __launch_bounds__(256) void k_mm_pool(
        const float* __restrict__ agg2, const float* __restrict__ W2,
        const float* __restrict__ b2, int N, float* __restrict__ pool) {
    __shared__ float sW[128 * 128];   // 64 KB
    __shared__ float sA[32 * 128];    // 16 KB (reused as reduction buffer at end)
    int t = threadIdx.x;
    for (int i = t; i < 128 * 128; i += 256) sW[i] = W2[i];
    int jg = t & 31;                  // j-group
    int rg = t >> 5;                  // row-group
    int j0 = jg * 4;
    int r0 = rg * 4;
    const float4 bbv = *(const float4*)&b2[j0];
    float4 poolAcc = make_float4(0.f, 0.f, 0.f, 0.f);

    for (int base = blockIdx.x * 32; base < N; base += gridDim.x * 32) {
        __syncthreads();                       // previous tile fully consumed (and sW ready, iter 0)
        int nn  = N - base; if (nn > 32) nn = 32;
        int lim = nn * 128;
        for (int i = t; i < 32 * 128; i += 256)
            sA[i] = (i < lim) ? agg2[base * 128 + i] : 0.f;
        __syncthreads();

        float4 acc0 = bbv, acc1 = bbv, acc2 = bbv, acc3 = bbv;
        #pragma unroll
        for (int k = 0; k < 128; k += 4) {
            const float4 w0 = *(const float4*)&sW[(k + 0) * 128 + j0];
            const float4 w1 = *(const float4*)&sW[(k + 1) * 128 + j0];
            const float4 w2 = *(const float4*)&sW[(k + 2) * 128 + j0];
            const float4 w3 = *(const float4*)&sW[(k + 3) * 128 + j0];
            const float4 r0v = *(const float4*)&sA[(r0 + 0) * 128 + k];
            const float4 r1v = *(const float4*)&sA[(r0 + 1) * 128 + k];
            const float4 r2v = *(const float4*)&sA[(r0 + 2) * 128 + k];
            const float4 r3v = *(const float4*)&sA[(r0 + 3) * 128 + k];
            #define FMA_ROW(accv, rv)                                              \
                accv.x = fmaf(rv.x, w0.x, accv.x); accv.y = fmaf(rv.x, w0.y, accv.y); \
                accv.z = fmaf(rv.x, w0.z, accv.z); accv.w = fmaf(rv.x, w0.w, accv.w); \
                accv.x = fmaf(rv.y, w1.x, accv.x); accv.y = fmaf(rv.y, w1.y, accv.y); \
                accv.z = fmaf(rv.y, w1.z, accv.z); accv.w = fmaf(rv.y, w1.w, accv.w); \
                accv.x = fmaf(rv.z, w2.x, accv.x); accv.y = fmaf(rv.z, w2.y, accv.y); \
                accv.z = fmaf(rv.z, w2.z, accv.z); accv.w = fmaf(rv.z, w2.w, accv.w); \
                accv.x = fmaf(rv.w, w3.x, accv.x); accv.y = fmaf(rv.w, w3.y, accv.y); \
                accv.z = fmaf(rv.w, w3.z, accv.z); accv.w = fmaf(rv.w, w3.w, accv.w);
            FMA_ROW(acc0, r0v)
            FMA_ROW(acc1, r1v)
            FMA_ROW(acc2, r2v)
            FMA_ROW(acc3, r3v)
            #undef FMA_ROW
        }
        int node = base + r0;
        if (node + 0 < N) { poolAcc.x += fmaxf(acc0.x, 0.f); poolAcc.y += fmaxf(acc0.y, 0.f);
                            poolAcc.z += fmaxf(acc0.z, 0.f); poolAcc.w += fmaxf(acc0.w, 0.f); }
        if (node + 1 < N) { poolAcc.x += fmaxf(acc1.x, 0.f); poolAcc.y += fmaxf(acc1.y, 0.f);
                            poolAcc.z += fmaxf(acc1.z, 0.f); poolAcc.w += fmaxf(acc1.w, 0.f); }
        if (node + 2 < N) { poolAcc.x += fmaxf(acc2.x, 0.f); poolAcc.y += fmaxf(acc2.y, 0.f);
                            poolAcc.z += fmaxf(acc2.z, 0.f); poolAcc.w += fmaxf(acc2.w, 0.f); }
        if (node + 3 < N) { poolAcc.x += fmaxf(acc3.x, 0.f); poolAcc.y += fmaxf(acc3.y, 0.f);
                            poolAcc.z += fmaxf(acc3.z, 0.f); poolAcc.w += fmaxf(acc3.w, 0.f); }
    }

    // block-level reduce over row-groups, then one atomic per feature
    __syncthreads();
    float* sR = sA;                            // reuse first 4 KB: [128 j][8 rg]
    sR[(j0 + 0) * 8 + rg] = poolAcc.x;
    sR[(j0 + 1) * 8 + rg] = poolAcc.y;
    sR[(j0 + 2) * 8 + rg] = poolAcc.z;
    sR[(j0 + 3) * 8 + rg] = poolAcc.w;
    __syncthreads();
    if (t < 128) {
        float s = 0.f;
        #pragma unroll
        for (int r = 0; r < 8; ++r) s += sR[t * 8 + r];
        atomicAdd(&pool[t], s);
    }
}

// ---------------- final 257-dim dot ----------------
__global__ void k_final(const float* __restrict__ pool, const float* __restrict__ phys,
                        const float* __restrict__ Wfc, const float* __restrict__ bfc,
                        float* __restrict__ out) {
    __shared__ float sm[256];
    int t = threadIdx.x;
    float acc = pool[t] * Wfc[t];
    if (t == 0) acc += phys[0] * Wfc[256] + bfc[0];
    sm[t] = acc;
    __syncthreads();
    for (int off = 128; off > 0; off >>= 1) {
        if (t < off) sm[t] += sm[t + off];
        __syncthreads();
    }
    if (t == 0) out[0] = sm[0];
}

extern "C" void kernel_launch(void* const* d_in, const int* in_sizes, int n_in,
                              void* d_out, int out_size, void* d_ws, size_t ws_size,
                              hipStream_t stream) {
    const float* mol_x  = (const float*)d_in[0];
    const int*   mol_e  = (const int*)  d_in[1];
    const float* prot_x = (const float*)d_in[2];
    const int*   prot_e = (const int*)  d_in[3];
    const float* phys   = (const float*)d_in[4];
    const float* W1     = (const float*)d_in[5];
    const float* b1     = (const float*)d_in[6];
    const float* W2     = (const float*)d_in[7];
    const float* b2     = (const float*)d_in[8];
    const float* Wfc    = (const float*)d_in[9];
    const float* bfc    = (const float*)d_in[10];
    float* out = (float*)d_out;

    int Nm = in_sizes[0], Em = in_sizes[1] / 2;
    int Np = in_sizes[2], Ep = in_sizes[3] / 2;
    int maxN = (Nm > Np) ? Nm : Np;
    int maxE = (Em > Ep) ? Em : Ep;

    char* p = (char*)d_ws;
    auto alloc = [&](size_t bytes) -> char* {
        char* r = p;
        p += (bytes + 255) & ~(size_t)255;
        return r;
    };
    float*  agg2     = (float*) alloc((size_t)maxN * 128 * 4);
    int*    sorted   = (int*)   alloc((size_t)maxE * 4);
    int*    hist     = (int*)   alloc((size_t)maxN * 4);
    int*    rowst    = (int*)   alloc((size_t)maxN * 4);
    int*    cursor   = (int*)   alloc((size_t)maxN * 4);
    int*    tilesums = (int*)   alloc(1024 * 4);
    float*  inv      = (float*) alloc((size_t)maxN * 4);
    float2* si       = (float2*)alloc((size_t)maxN * 8);
    float*  xi       = (float*) alloc((size_t)maxN * 4);
    float*  pool     = (float*) alloc(256 * 4);

    hipMemsetAsync(pool, 0, 256 * 4, stream);

    auto branch = [&](const float* x, const int* edge, int N, int E, float* poolOut) {
        const int* srcp = edge;
        const int* dstp = edge + E;
        hipMemsetAsync(hist, 0, (size_t)N * 4, stream);
        k_hist<<<CDIV(E, 256), 256, 0, stream>>>(dstp, E, hist);
        int B = CDIV(N, 256);
        k_scan_tile<<<B, 256, 0, stream>>>(hist, N, rowst, tilesums);
        k_scan_sums<<<1, 512, 0, stream>>>(tilesums, B);
        k_scan_add<<<B, 256, 0, stream>>>(rowst, N, tilesums, cursor);
        k_inv<<<CDIV(N, 256), 256, 0, stream>>>(hist, x, N, inv, xi);
        k_scatter<<<CDIV(E, 256), 256, 0, stream>>>(srcp, dstp, E, cursor, sorted);
        k_s<<<CDIV(N, 256), 256, 0, stream>>>(sorted, rowst, hist, xi, inv, N, si);
        k_agg2<<<4096, 256, 0, stream>>>(sorted, rowst, hist, si, W1, b1, N, agg2);
        k_mm_pool<<<512, 256, 0, stream>>>(agg2, W2, b2, N, poolOut);
    };
    branch(mol_x,  mol_e,  Nm, Em, pool);
    branch(prot_x, prot_e, Np, Ep, pool + 128);

    k_final<<<1, 256, 0, stream>>>(pool, phys, Wfc, bfc, out);
}

// Round 3
// 646.712 us; speedup vs baseline: 3.8643x; 3.8643x over previous
//
#include <hip/hip_runtime.h>

#define CDIV(a,b) (((a)+(b)-1)/(b))

// ---------------- histogram of dst (in-degree, without self loop) ----------------
__global__ void k_hist(const int* __restrict__ dst, int E, int* __restrict__ hist) {
    int e = blockIdx.x * 256 + threadIdx.x;
    if (e < E) atomicAdd(&hist[dst[e]], 1);
}

// ---------------- 2-level exclusive scan (tiles of 256) ----------------
__global__ void k_scan_tile(const int* __restrict__ in, int N,
                            int* __restrict__ out, int* __restrict__ tilesums) {
    __shared__ int sm[256];
    int t = threadIdx.x;
    int g = blockIdx.x * 256 + t;
    int v = (g < N) ? in[g] : 0;
    sm[t] = v;
    __syncthreads();
    for (int off = 1; off < 256; off <<= 1) {
        int x = sm[t];
        int y = (t >= off) ? sm[t - off] : 0;
        __syncthreads();
        sm[t] = x + y;
        __syncthreads();
    }
    int incl = sm[t];
    if (g < N) out[g] = incl - v;           // exclusive within tile
    if (t == 255) tilesums[blockIdx.x] = incl;
}

__global__ void k_scan_sums(int* __restrict__ sums, int B) {
    __shared__ int sm[512];
    int t = threadIdx.x;
    int v = (t < B) ? sums[t] : 0;
    sm[t] = v;
    __syncthreads();
    for (int off = 1; off < 512; off <<= 1) {
        int x = sm[t];
        int y = (t >= off) ? sm[t - off] : 0;
        __syncthreads();
        sm[t] = x + y;
        __syncthreads();
    }
    if (t < B) sums[t] = sm[t] - v;         // exclusive tile offsets
}

__global__ void k_scan_add(int* __restrict__ rowst, int N,
                           const int* __restrict__ sums, int* __restrict__ cursor) {
    int g = blockIdx.x * 256 + threadIdx.x;
    if (g < N) {
        int v = rowst[g] + sums[blockIdx.x];
        rowst[g] = v;
        cursor[g] = v;
    }
}

// ---------------- per-node: inv_sqrt(deg) and xi = x*inv ----------------
__global__ void k_inv(const int* __restrict__ hist, const float* __restrict__ x, int N,
                      float* __restrict__ inv, float* __restrict__ xi) {
    int i = blockIdx.x * 256 + threadIdx.x;
    if (i < N) {
        float iv = rsqrtf((float)(hist[i] + 1));   // +1 self loop
        inv[i] = iv;
        xi[i]  = x[i] * iv;
    }
}

// ---------------- scatter edges into CSR buckets ----------------
__global__ void k_scatter(const int* __restrict__ src, const int* __restrict__ dst, int E,
                          int* __restrict__ cursor, int* __restrict__ sorted) {
    int e = blockIdx.x * 256 + threadIdx.x;
    if (e < E) {
        int p = atomicAdd(&cursor[dst[e]], 1);
        sorted[p] = src[e];
    }
}

// ---------------- layer-1 scalar aggregation: si[d] = (s[d], inv[d]) ----------------
__global__ void k_s(const int* __restrict__ sorted, const int* __restrict__ rowst,
                    const int* __restrict__ cnt, const float* __restrict__ xi,
                    const float* __restrict__ inv, int N, float2* __restrict__ si) {
    int i = blockIdx.x * 256 + threadIdx.x;
    if (i < N) {
        int st = rowst[i], en = st + cnt[i];
        float acc = xi[i];                    // self-loop term
        int e = st;
        for (; e + 4 <= en; e += 4) {
            int n0 = sorted[e], n1 = sorted[e+1], n2 = sorted[e+2], n3 = sorted[e+3];
            float x0 = xi[n0], x1 = xi[n1], x2 = xi[n2], x3 = xi[n3];
            acc += (x0 + x1) + (x2 + x3);
        }
        for (; e < en; ++e) acc += xi[sorted[e]];
        float iv = inv[i];
        si[i] = make_float2(iv * acc, iv);
    }
}

// ---------------- layer-2 aggregation (pull, CSR): agg2[d,j] ----------------
// agg2[d,j] = inv[d]*( sum_{e->d} inv[src]*relu(s[src]*W1[j]+b1[j]) + inv[d]*relu(s[d]*W1[j]+b1[j]) )
__global__ __launch_bounds__(256) void k_agg2(
        const int* __restrict__ sorted, const int* __restrict__ rowst,
        const int* __restrict__ cnt, const float2* __restrict__ si,
        const float* __restrict__ W1, const float* __restrict__ b1,
        int N, float* __restrict__ agg2) {
    int j   = threadIdx.x & 127;
    int grp = threadIdx.x >> 7;               // 2 groups of 128 per block
    float w  = W1[j];
    float bb = b1[j];
    int stride = gridDim.x * 2;
    for (int d = blockIdx.x * 2 + grp; d < N; d += stride) {
        int st = rowst[d], en = st + cnt[d];
        float acc = 0.f;
        int e = st;
        for (; e + 4 <= en; e += 4) {
            int n0 = sorted[e], n1 = sorted[e+1], n2 = sorted[e+2], n3 = sorted[e+3];
            float2 p0 = si[n0];
            float2 p1 = si[n1];
            float2 p2 = si[n2];
            float2 p3 = si[n3];
            acc = fmaf(p0.y, fmaxf(fmaf(p0.x, w, bb), 0.f), acc);
            acc = fmaf(p1.y, fmaxf(fmaf(p1.x, w, bb), 0.f), acc);
            acc = fmaf(p2.y, fmaxf(fmaf(p2.x, w, bb), 0.f), acc);
            acc = fmaf(p3.y, fmaxf(fmaf(p3.x, w, bb), 0.f), acc);
        }
        for (; e < en; ++e) {
            float2 p = si[sorted[e]];
            acc = fmaf(p.y, fmaxf(fmaf(p.x, w, bb), 0.f), acc);
        }
        float2 ps = si[d];
        float oself = fmaxf(fmaf(ps.x, w, bb), 0.f);
        agg2[d * 128 + j] = ps.y * (acc + ps.y * oself);
    }
}

// ---------------- matmul + bias + relu + global-add-pool ----------------
// pool[j] += sum_d relu( agg2[d,:] @ W2[:,j] + b2[j] )
// One block per 64-row tile. 256 threads = 32 j-groups (4 j, float4) x 8 row-groups (8 rows).
// W2 in LDS (conflict-free b128); A rows read from GLOBAL (wave-broadcast, coalesced),
// double-buffered in registers with compile-time names (no runtime-indexed arrays).
__global__ __launch_bounds__(256, 2) void k_mm_pool(
        const float* __restrict__ agg2, const float* __restrict__ W2,
        const float* __restrict__ b2, int N, float* __restrict__ pool) {
    __shared__ float sW[128 * 128];   // 64 KB
    __shared__ float sR[8 * 128];     // 4 KB reduction buffer
    int t = threadIdx.x;
    {
        const float4* srcp = (const float4*)W2;
        float4* dstp = (float4*)sW;
        for (int i = t; i < 128 * 128 / 4; i += 256) dstp[i] = srcp[i];
    }
    __syncthreads();

    int jg = t & 31;
    int rg = t >> 5;
    int j0 = jg * 4;
    int r0 = blockIdx.x * 64 + rg * 8;
    const float4 bbv = *(const float4*)&b2[j0];

    const float* p0 = agg2 + (size_t)min(r0 + 0, N - 1) * 128;
    const float* p1 = agg2 + (size_t)min(r0 + 1, N - 1) * 128;
    const float* p2 = agg2 + (size_t)min(r0 + 2, N - 1) * 128;
    const float* p3 = agg2 + (size_t)min(r0 + 3, N - 1) * 128;
    const float* p4 = agg2 + (size_t)min(r0 + 4, N - 1) * 128;
    const float* p5 = agg2 + (size_t)min(r0 + 5, N - 1) * 128;
    const float* p6 = agg2 + (size_t)min(r0 + 6, N - 1) * 128;
    const float* p7 = agg2 + (size_t)min(r0 + 7, N - 1) * 128;

    float4 acc0 = bbv, acc1 = bbv, acc2 = bbv, acc3 = bbv;
    float4 acc4 = bbv, acc5 = bbv, acc6 = bbv, acc7 = bbv;
    float4 w0, w1, w2, w3;
    float4 xA0, xA1, xA2, xA3, xA4, xA5, xA6, xA7;
    float4 xB0, xB1, xB2, xB3, xB4, xB5, xB6, xB7;

#define LOADA(X, kk) \
    X##0 = *(const float4*)(p0 + (kk)); X##1 = *(const float4*)(p1 + (kk)); \
    X##2 = *(const float4*)(p2 + (kk)); X##3 = *(const float4*)(p3 + (kk)); \
    X##4 = *(const float4*)(p4 + (kk)); X##5 = *(const float4*)(p5 + (kk)); \
    X##6 = *(const float4*)(p6 + (kk)); X##7 = *(const float4*)(p7 + (kk));

#define WLOAD(kk) \
    w0 = *(const float4*)&sW[((kk) + 0) * 128 + j0]; \
    w1 = *(const float4*)&sW[((kk) + 1) * 128 + j0]; \
    w2 = *(const float4*)&sW[((kk) + 2) * 128 + j0]; \
    w3 = *(const float4*)&sW[((kk) + 3) * 128 + j0];

#define FMAROW(acc, av) \
    acc.x = fmaf(av.x, w0.x, acc.x); acc.y = fmaf(av.x, w0.y, acc.y); \
    acc.z = fmaf(av.x, w0.z, acc.z); acc.w = fmaf(av.x, w0.w, acc.w); \
    acc.x = fmaf(av.y, w1.x, acc.x); acc.y = fmaf(av.y, w1.y, acc.y); \
    acc.z = fmaf(av.y, w1.z, acc.z); acc.w = fmaf(av.y, w1.w, acc.w); \
    acc.x = fmaf(av.z, w2.x, acc.x); acc.y = fmaf(av.z, w2.y, acc.y); \
    acc.z = fmaf(av.z, w2.z, acc.z); acc.w = fmaf(av.z, w2.w, acc.w); \
    acc.x = fmaf(av.w, w3.x, acc.x); acc.y = fmaf(av.w, w3.y, acc.y); \
    acc.z = fmaf(av.w, w3.z, acc.z); acc.w = fmaf(av.w, w3.w, acc.w);

#define FMALL(X) \
    FMAROW(acc0, X##0) FMAROW(acc1, X##1) FMAROW(acc2, X##2) FMAROW(acc3, X##3) \
    FMAROW(acc4, X##4) FMAROW(acc5, X##5) FMAROW(acc6, X##6) FMAROW(acc7, X##7)

    LOADA(xA, 0)
    for (int k = 0; k < 128; k += 8) {
        LOADA(xB, k + 4)
        WLOAD(k)
        FMALL(xA)
        if (k + 8 < 128) { LOADA(xA, k + 8) }
        WLOAD(k + 4)
        FMALL(xB)
    }
#undef LOADA
#undef WLOAD
#undef FMAROW
#undef FMALL

    float4 pA = make_float4(0.f, 0.f, 0.f, 0.f);
#define POOLROW(i, acc) \
    if (r0 + i < N) { pA.x += fmaxf(acc.x, 0.f); pA.y += fmaxf(acc.y, 0.f); \
                      pA.z += fmaxf(acc.z, 0.f); pA.w += fmaxf(acc.w, 0.f); }
    POOLROW(0, acc0) POOLROW(1, acc1) POOLROW(2, acc2) POOLROW(3, acc3)
    POOLROW(4, acc4) POOLROW(5, acc5) POOLROW(6, acc6) POOLROW(7, acc7)
#undef POOLROW

    // block reduce: sR[rg][j] layout -> per-wave contiguous writes (no bank conflicts)
    *(float4*)&sR[rg * 128 + j0] = pA;
    __syncthreads();
    if (t < 128) {
        float s = 0.f;
        #pragma unroll
        for (int r = 0; r < 8; ++r) s += sR[r * 128 + t];
        atomicAdd(&pool[t], s);
    }
}

// ---------------- final 257-dim dot ----------------
__global__ void k_final(const float* __restrict__ pool, const float* __restrict__ phys,
                        const float* __restrict__ Wfc, const float* __restrict__ bfc,
                        float* __restrict__ out) {
    __shared__ float sm[256];
    int t = threadIdx.x;
    float acc = pool[t] * Wfc[t];
    if (t == 0) acc += phys[0] * Wfc[256] + bfc[0];
    sm[t] = acc;
    __syncthreads();
    for (int off = 128; off > 0; off >>= 1) {
        if (t < off) sm[t] += sm[t + off];
        __syncthreads();
    }
    if (t == 0) out[0] = sm[0];
}

extern "C" void kernel_launch(void* const* d_in, const int* in_sizes, int n_in,
                              void* d_out, int out_size, void* d_ws, size_t ws_size,
                              hipStream_t stream) {
    const float* mol_x  = (const float*)d_in[0];
    const int*   mol_e  = (const int*)  d_in[1];
    const float* prot_x = (const float*)d_in[2];
    const int*   prot_e = (const int*)  d_in[3];
    const float* phys   = (const float*)d_in[4];
    const float* W1     = (const float*)d_in[5];
    const float* b1     = (const float*)d_in[6];
    const float* W2     = (const float*)d_in[7];
    const float* b2     = (const float*)d_in[8];
    const float* Wfc    = (const float*)d_in[9];
    const float* bfc    = (const float*)d_in[10];
    float* out = (float*)d_out;

    int Nm = in_sizes[0], Em = in_sizes[1] / 2;
    int Np = in_sizes[2], Ep = in_sizes[3] / 2;
    int maxN = (Nm > Np) ? Nm : Np;
    int maxE = (Em > Ep) ? Em : Ep;

    char* p = (char*)d_ws;
    auto alloc = [&](size_t bytes) -> char* {
        char* r = p;
        p += (bytes + 255) & ~(size_t)255;
        return r;
    };
    float*  agg2     = (float*) alloc((size_t)maxN * 128 * 4);
    int*    sorted   = (int*)   alloc((size_t)maxE * 4);
    int*    hist     = (int*)   alloc((size_t)maxN * 4);
    int*    rowst    = (int*)   alloc((size_t)maxN * 4);
    int*    cursor   = (int*)   alloc((size_t)maxN * 4);
    int*    tilesums = (int*)   alloc(1024 * 4);
    float*  inv      = (float*) alloc((size_t)maxN * 4);
    float2* si       = (float2*)alloc((size_t)maxN * 8);
    float*  xi       = (float*) alloc((size_t)maxN * 4);
    float*  pool     = (float*) alloc(256 * 4);

    hipMemsetAsync(pool, 0, 256 * 4, stream);

    auto branch = [&](const float* x, const int* edge, int N, int E, float* poolOut) {
        const int* srcp = edge;
        const int* dstp = edge + E;
        hipMemsetAsync(hist, 0, (size_t)N * 4, stream);
        k_hist<<<CDIV(E, 256), 256, 0, stream>>>(dstp, E, hist);
        int B = CDIV(N, 256);
        k_scan_tile<<<B, 256, 0, stream>>>(hist, N, rowst, tilesums);
        k_scan_sums<<<1, 512, 0, stream>>>(tilesums, B);
        k_scan_add<<<B, 256, 0, stream>>>(rowst, N, tilesums, cursor);
        k_inv<<<CDIV(N, 256), 256, 0, stream>>>(hist, x, N, inv, xi);
        k_scatter<<<CDIV(E, 256), 256, 0, stream>>>(srcp, dstp, E, cursor, sorted);
        k_s<<<CDIV(N, 256), 256, 0, stream>>>(sorted, rowst, hist, xi, inv, N, si);
        k_agg2<<<4096, 256, 0, stream>>>(sorted, rowst, hist, si, W1, b1, N, agg2);
        k_mm_pool<<<CDIV(N, 64), 256, 0, stream>>>(agg2, W2, b2, N, poolOut);
    };
    branch(mol_x,  mol_e,  Nm, Em, pool);
    branch(prot_x, prot_e, Np, Ep, pool + 128);

    k_final<<<1, 256, 0, stream>>>(pool, phys, Wfc, bfc, out);
}

// Round 4
// 597.211 us; speedup vs baseline: 4.1845x; 1.0829x over previous
//
#include <hip/hip_runtime.h>

#define CDIV(a,b) (((a)+(b)-1)/(b))

// Combined node ids: mol [0,Nm), prot [Nm,Nm+Np).
// Combined edge positions: mol [0,Em), prot [Em,Em+Ep) (falls out of the global scan).

// ---------------- histogram of dst over BOTH graphs ----------------
__global__ void k_hist(const int* __restrict__ me, const int* __restrict__ pe,
                       int Em, int Ep, int Nm, int* __restrict__ hist) {
    int e = blockIdx.x * 256 + threadIdx.x;
    if (e >= Em + Ep) return;
    int d = (e < Em) ? me[Em + e] : (pe[Ep + (e - Em)] + Nm);
    atomicAdd(&hist[d], 1);
}

// ---------------- 2-level exclusive scan (tiles of 256) ----------------
__global__ void k_scan_tile(const int* __restrict__ in, int N,
                            int* __restrict__ out, int* __restrict__ tilesums) {
    __shared__ int sm[256];
    int t = threadIdx.x;
    int g = blockIdx.x * 256 + t;
    int v = (g < N) ? in[g] : 0;
    sm[t] = v;
    __syncthreads();
    for (int off = 1; off < 256; off <<= 1) {
        int x = sm[t];
        int y = (t >= off) ? sm[t - off] : 0;
        __syncthreads();
        sm[t] = x + y;
        __syncthreads();
    }
    int incl = sm[t];
    if (g < N) out[g] = incl - v;           // exclusive within tile
    if (t == 255) tilesums[blockIdx.x] = incl;
}

__global__ void k_scan_sums(int* __restrict__ sums, int B) {
    __shared__ int sm[1024];
    int t = threadIdx.x;
    int v = (t < B) ? sums[t] : 0;
    sm[t] = v;
    __syncthreads();
    for (int off = 1; off < 1024; off <<= 1) {
        int x = sm[t];
        int y = (t >= off) ? sm[t - off] : 0;
        __syncthreads();
        sm[t] = x + y;
        __syncthreads();
    }
    if (t < B) sums[t] = sm[t] - v;         // exclusive tile offsets
}

// rowst += tile offset; cursor = rowst; xi = x * rsqrt(deg+1)
__global__ void k_scan_add_inv(int* __restrict__ rowst, int Ntot,
                               const int* __restrict__ sums, int* __restrict__ cursor,
                               const int* __restrict__ hist,
                               const float* __restrict__ mx, const float* __restrict__ px,
                               int Nm, float* __restrict__ xi) {
    int g = blockIdx.x * 256 + threadIdx.x;
    if (g < Ntot) {
        int v = rowst[g] + sums[blockIdx.x];
        rowst[g] = v;
        cursor[g] = v;
        float x = (g < Nm) ? mx[g] : px[g - Nm];
        xi[g] = x * rsqrtf((float)(hist[g] + 1));
    }
}

// ---------------- scatter pass 1: xs[p] = xi[src] ----------------
__global__ void k_scatter1(const int* __restrict__ me, const int* __restrict__ pe,
                           int Em, int Ep, int Nm, const float* __restrict__ xi,
                           int* __restrict__ cursor, float* __restrict__ xs) {
    int e = blockIdx.x * 256 + threadIdx.x;
    if (e >= Em + Ep) return;
    int s, d;
    if (e < Em) { s = me[e];            d = me[Em + e]; }
    else        { int ee = e - Em; s = pe[ee] + Nm; d = pe[Ep + ee] + Nm; }
    int p = atomicAdd(&cursor[d], 1);
    xs[p] = xi[s];
}

// ---------------- layer-1 sum (sequential xs) + reset cursor ----------------
__global__ void k_s(const int* __restrict__ rowst, const int* __restrict__ hist,
                    const float* __restrict__ xs, const float* __restrict__ xi,
                    int Ntot, float2* __restrict__ si, int* __restrict__ cursor) {
    int i = blockIdx.x * 256 + threadIdx.x;
    if (i >= Ntot) return;
    int st = rowst[i], cnt = hist[i], en = st + cnt;
    float acc = xi[i];                    // self-loop term
    int e = st;
    for (; e + 4 <= en; e += 4) {
        float a = xs[e], b = xs[e + 1], c = xs[e + 2], d = xs[e + 3];
        acc += (a + b) + (c + d);
    }
    for (; e < en; ++e) acc += xs[e];
    float iv = rsqrtf((float)(cnt + 1));
    si[i] = make_float2(iv * acc, iv);
    cursor[i] = st;                       // rearm cursor for scatter pass 2
}

// ---------------- scatter pass 2 (per branch): sval[p-edgeBase] = si[src] ----------------
__global__ void k_scatter2(const int* __restrict__ edge, int E, int nodeBase, int edgeBase,
                           const float2* __restrict__ si, int* __restrict__ cursor,
                           float2* __restrict__ sval) {
    int e = blockIdx.x * 256 + threadIdx.x;
    if (e >= E) return;
    int s = edge[e] + nodeBase;
    int d = edge[E + e] + nodeBase;
    int p = atomicAdd(&cursor[d], 1);
    sval[p - edgeBase] = si[s];
}

// ---------------- layer-2 aggregation: one WAVE per node, 2 features/lane ----------------
// agg2[d,j] = inv[d]*( sum_e inv[src]*relu(s[src]*W1[j]+b1[j]) + inv[d]*relu(s[d]*W1[j]+b1[j]) )
__global__ __launch_bounds__(256) void k_agg2(
        const int* __restrict__ rowst, const int* __restrict__ hist,
        const float2* __restrict__ si, const float2* __restrict__ sval,
        const float* __restrict__ W1, const float* __restrict__ b1,
        int N, int nodeBase, int edgeBase, float* __restrict__ agg2) {
    int lane = threadIdx.x & 63;
    int wv   = (blockIdx.x * 256 + threadIdx.x) >> 6;
    int nW   = gridDim.x * 4;
    float wa = W1[lane],      wb = W1[lane + 64];
    float ba = b1[lane],      bbv = b1[lane + 64];
    for (int dl = wv; dl < N; dl += nW) {
        int g  = nodeBase + dl;
        int st = rowst[g] - edgeBase;
        int en = st + hist[g];
        float aa = 0.f, ab = 0.f;
        int e = st;
        for (; e + 8 <= en; e += 8) {
            float2 q0 = sval[e    ], q1 = sval[e + 1], q2 = sval[e + 2], q3 = sval[e + 3];
            float2 q4 = sval[e + 4], q5 = sval[e + 5], q6 = sval[e + 6], q7 = sval[e + 7];
            aa = fmaf(q0.y, fmaxf(fmaf(q0.x, wa, ba ), 0.f), aa);
            ab = fmaf(q0.y, fmaxf(fmaf(q0.x, wb, bbv), 0.f), ab);
            aa = fmaf(q1.y, fmaxf(fmaf(q1.x, wa, ba ), 0.f), aa);
            ab = fmaf(q1.y, fmaxf(fmaf(q1.x, wb, bbv), 0.f), ab);
            aa = fmaf(q2.y, fmaxf(fmaf(q2.x, wa, ba ), 0.f), aa);
            ab = fmaf(q2.y, fmaxf(fmaf(q2.x, wb, bbv), 0.f), ab);
            aa = fmaf(q3.y, fmaxf(fmaf(q3.x, wa, ba ), 0.f), aa);
            ab = fmaf(q3.y, fmaxf(fmaf(q3.x, wb, bbv), 0.f), ab);
            aa = fmaf(q4.y, fmaxf(fmaf(q4.x, wa, ba ), 0.f), aa);
            ab = fmaf(q4.y, fmaxf(fmaf(q4.x, wb, bbv), 0.f), ab);
            aa = fmaf(q5.y, fmaxf(fmaf(q5.x, wa, ba ), 0.f), aa);
            ab = fmaf(q5.y, fmaxf(fmaf(q5.x, wb, bbv), 0.f), ab);
            aa = fmaf(q6.y, fmaxf(fmaf(q6.x, wa, ba ), 0.f), aa);
            ab = fmaf(q6.y, fmaxf(fmaf(q6.x, wb, bbv), 0.f), ab);
            aa = fmaf(q7.y, fmaxf(fmaf(q7.x, wa, ba ), 0.f), aa);
            ab = fmaf(q7.y, fmaxf(fmaf(q7.x, wb, bbv), 0.f), ab);
        }
        for (; e < en; ++e) {
            float2 q = sval[e];
            aa = fmaf(q.y, fmaxf(fmaf(q.x, wa, ba ), 0.f), aa);
            ab = fmaf(q.y, fmaxf(fmaf(q.x, wb, bbv), 0.f), ab);
        }
        float2 ps = si[g];
        float oa = fmaxf(fmaf(ps.x, wa, ba ), 0.f);
        float ob = fmaxf(fmaf(ps.x, wb, bbv), 0.f);
        agg2[(size_t)dl * 128 + lane]      = ps.y * (aa + ps.y * oa);
        agg2[(size_t)dl * 128 + 64 + lane] = ps.y * (ab + ps.y * ob);
    }
}

// ---------------- matmul + bias + relu + global-add-pool ----------------
__global__ __launch_bounds__(256, 2) void k_mm_pool(
        const float* __restrict__ agg2, const float* __restrict__ W2,
        const float* __restrict__ b2, int N, float* __restrict__ pool) {
    __shared__ float sW[128 * 128];   // 64 KB
    __shared__ float sR[8 * 128];     // 4 KB reduction buffer
    int t = threadIdx.x;
    {
        const float4* srcp = (const float4*)W2;
        float4* dstp = (float4*)sW;
        for (int i = t; i < 128 * 128 / 4; i += 256) dstp[i] = srcp[i];
    }
    __syncthreads();

    int jg = t & 31;
    int rg = t >> 5;
    int j0 = jg * 4;
    int r0 = blockIdx.x * 64 + rg * 8;
    const float4 bbv = *(const float4*)&b2[j0];

    const float* p0 = agg2 + (size_t)min(r0 + 0, N - 1) * 128;
    const float* p1 = agg2 + (size_t)min(r0 + 1, N - 1) * 128;
    const float* p2 = agg2 + (size_t)min(r0 + 2, N - 1) * 128;
    const float* p3 = agg2 + (size_t)min(r0 + 3, N - 1) * 128;
    const float* p4 = agg2 + (size_t)min(r0 + 4, N - 1) * 128;
    const float* p5 = agg2 + (size_t)min(r0 + 5, N - 1) * 128;
    const float* p6 = agg2 + (size_t)min(r0 + 6, N - 1) * 128;
    const float* p7 = agg2 + (size_t)min(r0 + 7, N - 1) * 128;

    float4 acc0 = bbv, acc1 = bbv, acc2 = bbv, acc3 = bbv;
    float4 acc4 = bbv, acc5 = bbv, acc6 = bbv, acc7 = bbv;
    float4 w0, w1, w2, w3;
    float4 xA0, xA1, xA2, xA3, xA4, xA5, xA6, xA7;
    float4 xB0, xB1, xB2, xB3, xB4, xB5, xB6, xB7;

#define LOADA(X, kk) \
    X##0 = *(const float4*)(p0 + (kk)); X##1 = *(const float4*)(p1 + (kk)); \
    X##2 = *(const float4*)(p2 + (kk)); X##3 = *(const float4*)(p3 + (kk)); \
    X##4 = *(const float4*)(p4 + (kk)); X##5 = *(const float4*)(p5 + (kk)); \
    X##6 = *(const float4*)(p6 + (kk)); X##7 = *(const float4*)(p7 + (kk));

#define WLOAD(kk) \
    w0 = *(const float4*)&sW[((kk) + 0) * 128 + j0]; \
    w1 = *(const float4*)&sW[((kk) + 1) * 128 + j0]; \
    w2 = *(const float4*)&sW[((kk) + 2) * 128 + j0]; \
    w3 = *(const float4*)&sW[((kk) + 3) * 128 + j0];

#define FMAROW(acc, av) \
    acc.x = fmaf(av.x, w0.x, acc.x); acc.y = fmaf(av.x, w0.y, acc.y); \
    acc.z = fmaf(av.x, w0.z, acc.z); acc.w = fmaf(av.x, w0.w, acc.w); \
    acc.x = fmaf(av.y, w1.x, acc.x); acc.y = fmaf(av.y, w1.y, acc.y); \
    acc.z = fmaf(av.y, w1.z, acc.z); acc.w = fmaf(av.y, w1.w, acc.w); \
    acc.x = fmaf(av.z, w2.x, acc.x); acc.y = fmaf(av.z, w2.y, acc.y); \
    acc.z = fmaf(av.z, w2.z, acc.z); acc.w = fmaf(av.z, w2.w, acc.w); \
    acc.x = fmaf(av.w, w3.x, acc.x); acc.y = fmaf(av.w, w3.y, acc.y); \
    acc.z = fmaf(av.w, w3.z, acc.z); acc.w = fmaf(av.w, w3.w, acc.w);

#define FMALL(X) \
    FMAROW(acc0, X##0) FMAROW(acc1, X##1) FMAROW(acc2, X##2) FMAROW(acc3, X##3) \
    FMAROW(acc4, X##4) FMAROW(acc5, X##5) FMAROW(acc6, X##6) FMAROW(acc7, X##7)

    LOADA(xA, 0)
    for (int k = 0; k < 128; k += 8) {
        LOADA(xB, k + 4)
        WLOAD(k)
        FMALL(xA)
        if (k + 8 < 128) { LOADA(xA, k + 8) }
        WLOAD(k + 4)
        FMALL(xB)
    }
#undef LOADA
#undef WLOAD
#undef FMAROW
#undef FMALL

    float4 pA = make_float4(0.f, 0.f, 0.f, 0.f);
#define POOLROW(i, acc) \
    if (r0 + i < N) { pA.x += fmaxf(acc.x, 0.f); pA.y += fmaxf(acc.y, 0.f); \
                      pA.z += fmaxf(acc.z, 0.f); pA.w += fmaxf(acc.w, 0.f); }
    POOLROW(0, acc0) POOLROW(1, acc1) POOLROW(2, acc2) POOLROW(3, acc3)
    POOLROW(4, acc4) POOLROW(5, acc5) POOLROW(6, acc6) POOLROW(7, acc7)
#undef POOLROW

    *(float4*)&sR[rg * 128 + j0] = pA;
    __syncthreads();
    if (t < 128) {
        float s = 0.f;
        #pragma unroll
        for (int r = 0; r < 8; ++r) s += sR[r * 128 + t];
        atomicAdd(&pool[t], s);
    }
}

// ---------------- final 257-dim dot ----------------
__global__ void k_final(const float* __restrict__ pool, const float* __restrict__ phys,
                        const float* __restrict__ Wfc, const float* __restrict__ bfc,
                        float* __restrict__ out) {
    __shared__ float sm[256];
    int t = threadIdx.x;
    float acc = pool[t] * Wfc[t];
    if (t == 0) acc += phys[0] * Wfc[256] + bfc[0];
    sm[t] = acc;
    __syncthreads();
    for (int off = 128; off > 0; off >>= 1) {
        if (t < off) sm[t] += sm[t + off];
        __syncthreads();
    }
    if (t == 0) out[0] = sm[0];
}

extern "C" void kernel_launch(void* const* d_in, const int* in_sizes, int n_in,
                              void* d_out, int out_size, void* d_ws, size_t ws_size,
                              hipStream_t stream) {
    const float* mol_x  = (const float*)d_in[0];
    const int*   mol_e  = (const int*)  d_in[1];
    const float* prot_x = (const float*)d_in[2];
    const int*   prot_e = (const int*)  d_in[3];
    const float* phys   = (const float*)d_in[4];
    const float* W1     = (const float*)d_in[5];
    const float* b1     = (const float*)d_in[6];
    const float* W2     = (const float*)d_in[7];
    const float* b2     = (const float*)d_in[8];
    const float* Wfc    = (const float*)d_in[9];
    const float* bfc    = (const float*)d_in[10];
    float* out = (float*)d_out;

    int Nm = in_sizes[0], Em = in_sizes[1] / 2;
    int Np = in_sizes[2], Ep = in_sizes[3] / 2;
    int Ntot = Nm + Np, Etot = Em + Ep;
    int maxN = (Nm > Np) ? Nm : Np;
    int maxE = (Em > Ep) ? Em : Ep;

    char* p = (char*)d_ws;
    auto alloc = [&](size_t bytes) -> char* {
        char* r = p;
        p += (bytes + 255) & ~(size_t)255;
        return r;
    };
    float*  agg2  = (float*) alloc((size_t)maxN * 128 * 4);
    float2* sval  = (float2*)alloc((size_t)maxE * 8);   // pass1 aliases as float xs[Etot]
    size_t histBytes = ((size_t)Ntot * 4 + 255) & ~(size_t)255;
    int*    hist  = (int*)   alloc((size_t)Ntot * 4);
    float*  pool  = (float*) alloc(256 * 4);            // adjacent to hist: single memset
    int*    rowst = (int*)   alloc((size_t)Ntot * 4);
    int*    cursor= (int*)   alloc((size_t)Ntot * 4);
    int*    tiles = (int*)   alloc(4096);
    float*  xi    = (float*) alloc((size_t)Ntot * 4);
    float2* si    = (float2*)alloc((size_t)Ntot * 8);
    float*  xs    = (float*) sval;                       // alias (Etot*4 <= maxE*8)

    hipMemsetAsync(hist, 0, histBytes + 1024, stream);   // hist + pool

    int B = CDIV(Ntot, 256);
    k_hist        <<<CDIV(Etot, 256), 256, 0, stream>>>(mol_e, prot_e, Em, Ep, Nm, hist);
    k_scan_tile   <<<B, 256, 0, stream>>>(hist, Ntot, rowst, tiles);
    k_scan_sums   <<<1, 1024, 0, stream>>>(tiles, B);
    k_scan_add_inv<<<B, 256, 0, stream>>>(rowst, Ntot, tiles, cursor, hist,
                                          mol_x, prot_x, Nm, xi);
    k_scatter1    <<<CDIV(Etot, 256), 256, 0, stream>>>(mol_e, prot_e, Em, Ep, Nm,
                                                        xi, cursor, xs);
    k_s           <<<B, 256, 0, stream>>>(rowst, hist, xs, xi, Ntot, si, cursor);

    // mol branch
    k_scatter2<<<CDIV(Em, 256), 256, 0, stream>>>(mol_e, Em, 0, 0, si, cursor, sval);
    k_agg2    <<<2048, 256, 0, stream>>>(rowst, hist, si, sval, W1, b1, Nm, 0, 0, agg2);
    k_mm_pool <<<CDIV(Nm, 64), 256, 0, stream>>>(agg2, W2, b2, Nm, pool);
    // prot branch (reuses sval/agg2 buffers)
    k_scatter2<<<CDIV(Ep, 256), 256, 0, stream>>>(prot_e, Ep, Nm, Em, si, cursor, sval);
    k_agg2    <<<2048, 256, 0, stream>>>(rowst, hist, si, sval, W1, b1, Np, Nm, Em, agg2);
    k_mm_pool <<<CDIV(Np, 64), 256, 0, stream>>>(agg2, W2, b2, Np, pool + 128);

    k_final<<<1, 256, 0, stream>>>(pool, phys, Wfc, bfc, out);
}

// Round 5
// 524.966 us; speedup vs baseline: 4.7604x; 1.1376x over previous
//
#include <hip/hip_runtime.h>

#define CDIV(a,b) (((a)+(b)-1)/(b))

// Combined node ids: mol [0,Nm), prot [Nm,Nm+Np).
// Combined edge slots: mol edges land in [0,Em), prot in [Em,Etot) via the global scan.

// ---------------- histogram of dst over BOTH graphs ----------------
__global__ void k_hist(const int* __restrict__ me, const int* __restrict__ pe,
                       int Em, int Ep, int Nm, int* __restrict__ hist) {
    int e = blockIdx.x * 256 + threadIdx.x;
    if (e >= Em + Ep) return;
    int d = (e < Em) ? me[Em + e] : (pe[Ep + (e - Em)] + Nm);
    atomicAdd(&hist[d], 1);
}

// ---------------- 2-level exclusive scan (tiles of 256) ----------------
__global__ void k_scan_tile(const int* __restrict__ in, int N,
                            int* __restrict__ out, int* __restrict__ tilesums) {
    __shared__ int sm[256];
    int t = threadIdx.x;
    int g = blockIdx.x * 256 + t;
    int v = (g < N) ? in[g] : 0;
    sm[t] = v;
    __syncthreads();
    for (int off = 1; off < 256; off <<= 1) {
        int x = sm[t];
        int y = (t >= off) ? sm[t - off] : 0;
        __syncthreads();
        sm[t] = x + y;
        __syncthreads();
    }
    int incl = sm[t];
    if (g < N) out[g] = incl - v;           // exclusive within tile
    if (t == 255) tilesums[blockIdx.x] = incl;
}

__global__ void k_scan_sums(int* __restrict__ sums, int B) {
    __shared__ int sm[1024];
    int t = threadIdx.x;
    int v = (t < B) ? sums[t] : 0;
    sm[t] = v;
    __syncthreads();
    for (int off = 1; off < 1024; off <<= 1) {
        int x = sm[t];
        int y = (t >= off) ? sm[t - off] : 0;
        __syncthreads();
        sm[t] = x + y;
        __syncthreads();
    }
    if (t < B) sums[t] = sm[t] - v;         // exclusive tile offsets
}

// rowst += tile offset; cursor = rowst; xi = x * rsqrt(deg+1)
__global__ void k_scan_add_inv(int* __restrict__ rowst, int Ntot,
                               const int* __restrict__ sums, int* __restrict__ cursor,
                               const int* __restrict__ hist,
                               const float* __restrict__ mx, const float* __restrict__ px,
                               int Nm, float* __restrict__ xi) {
    int g = blockIdx.x * 256 + threadIdx.x;
    if (g < Ntot) {
        int v = rowst[g] + sums[blockIdx.x];
        rowst[g] = v;
        cursor[g] = v;
        float x = (g < Nm) ? mx[g] : px[g - Nm];
        xi[g] = x * rsqrtf((float)(hist[g] + 1));
    }
}

// ---------------- single edge pass: CSR index scatter + layer-1 atomic push ----------------
// sorted[p] = src (the only remaining scattered write);  s_acc[d] += xi[src] (fire-and-forget).
__global__ void k_build(const int* __restrict__ me, const int* __restrict__ pe,
                        int Em, int Ep, int Nm, const float* __restrict__ xi,
                        int* __restrict__ cursor, int* __restrict__ sorted,
                        float* __restrict__ s_acc) {
    int e = blockIdx.x * 256 + threadIdx.x;
    if (e >= Em + Ep) return;
    int s, d;
    if (e < Em) { s = me[e];            d = me[Em + e]; }
    else        { int ee = e - Em; s = pe[ee] + Nm; d = pe[Ep + ee] + Nm; }
    int p = atomicAdd(&cursor[d], 1);
    sorted[p] = s;
    atomicAdd(&s_acc[d], xi[s]);
}

// ---------------- layer-1 finalize: si[d] = (inv*(s_acc+xi), inv) ----------------
__global__ void k_s(const int* __restrict__ hist, const float* __restrict__ s_acc,
                    const float* __restrict__ xi, int Ntot, float2* __restrict__ si) {
    int i = blockIdx.x * 256 + threadIdx.x;
    if (i >= Ntot) return;
    float iv = rsqrtf((float)(hist[i] + 1));
    si[i] = make_float2(iv * (s_acc[i] + xi[i]), iv);
}

// ---------------- layer-2 aggregation: one WAVE per node, gather si from L2 ----------------
// agg2[d,j] = inv[d]*( sum_e inv[src]*relu(s[src]*W1[j]+b1[j]) + inv[d]*relu(s[d]*W1[j]+b1[j]) )
// 64-wide index load (coalesced) + 64-wide si gather (one instr, 64 lines in flight),
// then register broadcast via __shfl (readlane) — no LDS, no dependent scalar chain.
__global__ __launch_bounds__(256) void k_agg2(
        const int* __restrict__ rowst, const int* __restrict__ hist,
        const float2* __restrict__ si, const int* __restrict__ sorted,
        const float* __restrict__ W1, const float* __restrict__ b1,
        int Ntot, float* __restrict__ agg2) {
    int lane = threadIdx.x & 63;
    int wv   = (blockIdx.x * 256 + threadIdx.x) >> 6;
    int nW   = gridDim.x * 4;
    float wa = W1[lane],  wb  = W1[lane + 64];
    float ba = b1[lane],  bbv = b1[lane + 64];
    for (int d = wv; d < Ntot; d += nW) {
        int st  = rowst[d];
        int cnt = hist[d];
        float aa = 0.f, ab = 0.f;
        for (int b0 = 0; b0 < cnt; b0 += 64) {
            int take = cnt - b0; if (take > 64) take = 64;
            int l = (lane < take) ? lane : 0;
            int idx = sorted[st + b0 + l];
            float2 sv = si[idx];
            for (int i = 0; i < take; ++i) {
                float s_i = __shfl(sv.x, i);
                float v_i = __shfl(sv.y, i);
                aa = fmaf(v_i, fmaxf(fmaf(s_i, wa, ba ), 0.f), aa);
                ab = fmaf(v_i, fmaxf(fmaf(s_i, wb, bbv), 0.f), ab);
            }
        }
        float2 ps = si[d];
        float oa = fmaxf(fmaf(ps.x, wa, ba ), 0.f);
        float ob = fmaxf(fmaf(ps.x, wb, bbv), 0.f);
        agg2[(size_t)d * 128 + lane]      = ps.y * (aa + ps.y * oa);
        agg2[(size_t)d * 128 + 64 + lane] = ps.y * (ab + ps.y * ob);
    }
}

// ---------------- matmul + bias + relu + global-add-pool ----------------
__global__ __launch_bounds__(256, 2) void k_mm_pool(
        const float* __restrict__ agg2, const float* __restrict__ W2,
        const float* __restrict__ b2, int N, float* __restrict__ pool) {
    __shared__ float sW[128 * 128];   // 64 KB
    __shared__ float sR[8 * 128];     // 4 KB reduction buffer
    int t = threadIdx.x;
    {
        const float4* srcp = (const float4*)W2;
        float4* dstp = (float4*)sW;
        for (int i = t; i < 128 * 128 / 4; i += 256) dstp[i] = srcp[i];
    }
    __syncthreads();

    int jg = t & 31;
    int rg = t >> 5;
    int j0 = jg * 4;
    int r0 = blockIdx.x * 64 + rg * 8;
    const float4 bbv = *(const float4*)&b2[j0];

    const float* p0 = agg2 + (size_t)min(r0 + 0, N - 1) * 128;
    const float* p1 = agg2 + (size_t)min(r0 + 1, N - 1) * 128;
    const float* p2 = agg2 + (size_t)min(r0 + 2, N - 1) * 128;
    const float* p3 = agg2 + (size_t)min(r0 + 3, N - 1) * 128;
    const float* p4 = agg2 + (size_t)min(r0 + 4, N - 1) * 128;
    const float* p5 = agg2 + (size_t)min(r0 + 5, N - 1) * 128;
    const float* p6 = agg2 + (size_t)min(r0 + 6, N - 1) * 128;
    const float* p7 = agg2 + (size_t)min(r0 + 7, N - 1) * 128;

    float4 acc0 = bbv, acc1 = bbv, acc2 = bbv, acc3 = bbv;
    float4 acc4 = bbv, acc5 = bbv, acc6 = bbv, acc7 = bbv;
    float4 w0, w1, w2, w3;
    float4 xA0, xA1, xA2, xA3, xA4, xA5, xA6, xA7;
    float4 xB0, xB1, xB2, xB3, xB4, xB5, xB6, xB7;

#define LOADA(X, kk) \
    X##0 = *(const float4*)(p0 + (kk)); X##1 = *(const float4*)(p1 + (kk)); \
    X##2 = *(const float4*)(p2 + (kk)); X##3 = *(const float4*)(p3 + (kk)); \
    X##4 = *(const float4*)(p4 + (kk)); X##5 = *(const float4*)(p5 + (kk)); \
    X##6 = *(const float4*)(p6 + (kk)); X##7 = *(const float4*)(p7 + (kk));

#define WLOAD(kk) \
    w0 = *(const float4*)&sW[((kk) + 0) * 128 + j0]; \
    w1 = *(const float4*)&sW[((kk) + 1) * 128 + j0]; \
    w2 = *(const float4*)&sW[((kk) + 2) * 128 + j0]; \
    w3 = *(const float4*)&sW[((kk) + 3) * 128 + j0];

#define FMAROW(acc, av) \
    acc.x = fmaf(av.x, w0.x, acc.x); acc.y = fmaf(av.x, w0.y, acc.y); \
    acc.z = fmaf(av.x, w0.z, acc.z); acc.w = fmaf(av.x, w0.w, acc.w); \
    acc.x = fmaf(av.y, w1.x, acc.x); acc.y = fmaf(av.y, w1.y, acc.y); \
    acc.z = fmaf(av.y, w1.z, acc.z); acc.w = fmaf(av.y, w1.w, acc.w); \
    acc.x = fmaf(av.z, w2.x, acc.x); acc.y = fmaf(av.z, w2.y, acc.y); \
    acc.z = fmaf(av.z, w2.z, acc.z); acc.w = fmaf(av.z, w2.w, acc.w); \
    acc.x = fmaf(av.w, w3.x, acc.x); acc.y = fmaf(av.w, w3.y, acc.y); \
    acc.z = fmaf(av.w, w3.z, acc.z); acc.w = fmaf(av.w, w3.w, acc.w);

#define FMALL(X) \
    FMAROW(acc0, X##0) FMAROW(acc1, X##1) FMAROW(acc2, X##2) FMAROW(acc3, X##3) \
    FMAROW(acc4, X##4) FMAROW(acc5, X##5) FMAROW(acc6, X##6) FMAROW(acc7, X##7)

    LOADA(xA, 0)
    for (int k = 0; k < 128; k += 8) {
        LOADA(xB, k + 4)
        WLOAD(k)
        FMALL(xA)
        if (k + 8 < 128) { LOADA(xA, k + 8) }
        WLOAD(k + 4)
        FMALL(xB)
    }
#undef LOADA
#undef WLOAD
#undef FMAROW
#undef FMALL

    float4 pA = make_float4(0.f, 0.f, 0.f, 0.f);
#define POOLROW(i, acc) \
    if (r0 + i < N) { pA.x += fmaxf(acc.x, 0.f); pA.y += fmaxf(acc.y, 0.f); \
                      pA.z += fmaxf(acc.z, 0.f); pA.w += fmaxf(acc.w, 0.f); }
    POOLROW(0, acc0) POOLROW(1, acc1) POOLROW(2, acc2) POOLROW(3, acc3)
    POOLROW(4, acc4) POOLROW(5, acc5) POOLROW(6, acc6) POOLROW(7, acc7)
#undef POOLROW

    *(float4*)&sR[rg * 128 + j0] = pA;
    __syncthreads();
    if (t < 128) {
        float s = 0.f;
        #pragma unroll
        for (int r = 0; r < 8; ++r) s += sR[r * 128 + t];
        atomicAdd(&pool[t], s);
    }
}

// ---------------- final 257-dim dot ----------------
__global__ void k_final(const float* __restrict__ pool, const float* __restrict__ phys,
                        const float* __restrict__ Wfc, const float* __restrict__ bfc,
                        float* __restrict__ out) {
    __shared__ float sm[256];
    int t = threadIdx.x;
    float acc = pool[t] * Wfc[t];
    if (t == 0) acc += phys[0] * Wfc[256] + bfc[0];
    sm[t] = acc;
    __syncthreads();
    for (int off = 128; off > 0; off >>= 1) {
        if (t < off) sm[t] += sm[t + off];
        __syncthreads();
    }
    if (t == 0) out[0] = sm[0];
}

extern "C" void kernel_launch(void* const* d_in, const int* in_sizes, int n_in,
                              void* d_out, int out_size, void* d_ws, size_t ws_size,
                              hipStream_t stream) {
    const float* mol_x  = (const float*)d_in[0];
    const int*   mol_e  = (const int*)  d_in[1];
    const float* prot_x = (const float*)d_in[2];
    const int*   prot_e = (const int*)  d_in[3];
    const float* phys   = (const float*)d_in[4];
    const float* W1     = (const float*)d_in[5];
    const float* b1     = (const float*)d_in[6];
    const float* W2     = (const float*)d_in[7];
    const float* b2     = (const float*)d_in[8];
    const float* Wfc    = (const float*)d_in[9];
    const float* bfc    = (const float*)d_in[10];
    float* out = (float*)d_out;

    int Nm = in_sizes[0], Em = in_sizes[1] / 2;
    int Np = in_sizes[2], Ep = in_sizes[3] / 2;
    int Ntot = Nm + Np, Etot = Em + Ep;

    char* p = (char*)d_ws;
    auto alloc = [&](size_t bytes) -> char* {
        char* r = p;
        p += (bytes + 255) & ~(size_t)255;
        return r;
    };
    float*  agg2  = (float*) alloc((size_t)Ntot * 128 * 4);   // 76.8 MB
    int*    sorted= (int*)   alloc((size_t)Etot * 4);         //  9.6 MB
    int*    hist  = (int*)   alloc((size_t)Ntot * 4);         // ---- memset region start
    float*  s_acc = (float*) alloc((size_t)Ntot * 4);
    float*  pool  = (float*) alloc(256 * 4);                  // ---- memset region end
    int*    rowst = (int*)   alloc((size_t)Ntot * 4);
    int*    cursor= (int*)   alloc((size_t)Ntot * 4);
    int*    tiles = (int*)   alloc(4096);
    float*  xi    = (float*) alloc((size_t)Ntot * 4);
    float2* si    = (float2*)alloc((size_t)Ntot * 8);

    size_t zbytes = (char*)(pool + 256) - (char*)hist;
    hipMemsetAsync(hist, 0, zbytes, stream);                  // hist + s_acc + pool

    int B  = CDIV(Ntot, 256);
    int EB = CDIV(Etot, 256);
    k_hist        <<<EB, 256, 0, stream>>>(mol_e, prot_e, Em, Ep, Nm, hist);
    k_scan_tile   <<<B, 256, 0, stream>>>(hist, Ntot, rowst, tiles);
    k_scan_sums   <<<1, 1024, 0, stream>>>(tiles, B);
    k_scan_add_inv<<<B, 256, 0, stream>>>(rowst, Ntot, tiles, cursor, hist,
                                          mol_x, prot_x, Nm, xi);
    k_build       <<<EB, 256, 0, stream>>>(mol_e, prot_e, Em, Ep, Nm,
                                           xi, cursor, sorted, s_acc);
    k_s           <<<B, 256, 0, stream>>>(hist, s_acc, xi, Ntot, si);
    k_agg2        <<<4096, 256, 0, stream>>>(rowst, hist, si, sorted, W1, b1, Ntot, agg2);
    k_mm_pool     <<<CDIV(Nm, 64), 256, 0, stream>>>(agg2, W2, b2, Nm, pool);
    k_mm_pool     <<<CDIV(Np, 64), 256, 0, stream>>>(agg2 + (size_t)Nm * 128, W2, b2,
                                                     Np, pool + 128);
    k_final       <<<1, 256, 0, stream>>>(pool, phys, Wfc, bfc, out);
}

// Round 6
// 472.923 us; speedup vs baseline: 5.2843x; 1.1100x over previous
//
#include <hip/hip_runtime.h>

#define CDIV(a,b) (((a)+(b)-1)/(b))

// Combined node ids: mol [0,Nm), prot [Nm,Nm+Np).
// Fast path (b1 == 0, checked on device): relu(s*w) = w+*s+ + w-*s- is bilinear,
// so layer-2 aggregation needs only P[d]=sum inv_s*s+, M[d]=sum inv_s*s- and the
// 128x128 matmul collapses to rank-2: pre2[d,:] = A_d*u + B_d*v + b2.
// Fallback path (b1 != 0): round-5 CSR pipeline, guarded by flags[0].

// ---------------- flag: is b1 nonzero anywhere? ----------------
__global__ void k_flag(const float* __restrict__ b1, int* __restrict__ flags) {
    __shared__ int nz;
    if (threadIdx.x == 0) nz = 0;
    __syncthreads();
    if (threadIdx.x < 128 && b1[threadIdx.x] != 0.f) atomicOr(&nz, 1);
    __syncthreads();
    if (threadIdx.x == 0) flags[0] = nz;
}

// ---------------- histogram of dst over BOTH graphs ----------------
__global__ void k_hist(const int* __restrict__ me, const int* __restrict__ pe,
                       int Em, int Ep, int Nm, int* __restrict__ hist) {
    int e = blockIdx.x * 256 + threadIdx.x;
    if (e >= Em + Ep) return;
    int d = (e < Em) ? me[Em + e] : (pe[Ep + (e - Em)] + Nm);
    atomicAdd(&hist[d], 1);
}

// ---------------- per-node: inv = rsqrt(deg+1), xi = x*inv ----------------
__global__ void k_inv(const int* __restrict__ hist,
                      const float* __restrict__ mx, const float* __restrict__ px,
                      int Nm, int Ntot, float* __restrict__ xi) {
    int g = blockIdx.x * 256 + threadIdx.x;
    if (g < Ntot) {
        float x = (g < Nm) ? mx[g] : px[g - Nm];
        xi[g] = x * rsqrtf((float)(hist[g] + 1));
    }
}

// ---------------- edge pass 2: layer-1 push s_acc[d] += xi[src] ----------------
__global__ void k_push1(const int* __restrict__ me, const int* __restrict__ pe,
                        int Em, int Ep, int Nm, const float* __restrict__ xi,
                        float* __restrict__ s_acc) {
    int e = blockIdx.x * 256 + threadIdx.x;
    if (e >= Em + Ep) return;
    int s, d;
    if (e < Em) { s = me[e];            d = me[Em + e]; }
    else        { int ee = e - Em; s = pe[ee] + Nm; d = pe[Ep + ee] + Nm; }
    atomicAdd(&s_acc[d], xi[s]);
}

// ---------------- layer-1 finalize: si[d] = (inv*(s_acc+xi), inv) ----------------
__global__ void k_s(const int* __restrict__ hist, const float* __restrict__ s_acc,
                    const float* __restrict__ xi, int Ntot, float2* __restrict__ si) {
    int i = blockIdx.x * 256 + threadIdx.x;
    if (i >= Ntot) return;
    float iv = rsqrtf((float)(hist[i] + 1));
    si[i] = make_float2(iv * (s_acc[i] + xi[i]), iv);
}

// ---------------- edge pass 3 (fast): PM push, ONE atomic per edge ----------------
__global__ void k_push2(const int* __restrict__ me, const int* __restrict__ pe,
                        int Em, int Ep, int Nm, const float2* __restrict__ si,
                        float* __restrict__ PM, const int* __restrict__ flags) {
    if (flags[0]) return;
    int e = blockIdx.x * 256 + threadIdx.x;
    if (e >= Em + Ep) return;
    int s, d;
    if (e < Em) { s = me[e];            d = me[Em + e]; }
    else        { int ee = e - Em; s = pe[ee] + Nm; d = pe[Ep + ee] + Nm; }
    float2 q = si[s];                       // (s_value, inv)
    float val = q.y * q.x;                  // inv*s (signed)
    if (val > 0.f)      atomicAdd(&PM[2 * d],     val);   // P: inv*s+
    else if (val < 0.f) atomicAdd(&PM[2 * d + 1], -val);  // M: inv*s-
}

// ---------------- fast: u = W1+ @ W2, v = W1- @ W2 ----------------
__global__ void k_uv(const float* __restrict__ W1, const float* __restrict__ W2,
                     float* __restrict__ u, float* __restrict__ v,
                     const int* __restrict__ flags) {
    if (flags[0]) return;
    int k = threadIdx.x;                    // 128 threads
    float au = 0.f, av = 0.f;
    for (int j = 0; j < 128; ++j) {
        float w = W1[j];
        float w2 = W2[j * 128 + k];
        au = fmaf(fmaxf(w, 0.f), w2, au);
        av = fmaf(fmaxf(-w, 0.f), w2, av);
    }
    u[k] = au;
    v[k] = av;
}

// ---------------- fast: pooled output directly from (si, PM) ----------------
// pre2[d,k] = A_d*u_k + B_d*v_k + b2_k;  pool_k += relu(pre2)  (split mol/prot)
__global__ __launch_bounds__(256) void k_pool_fact(
        const float2* __restrict__ si, const float* __restrict__ PM,
        const float* __restrict__ u, const float* __restrict__ v,
        const float* __restrict__ b2, int Nm, int Ntot,
        float* __restrict__ pool, const int* __restrict__ flags) {
    if (flags[0]) return;
    __shared__ float sm[2][2][128];
    int t = threadIdx.x;
    int lane = t & 127;
    int grp  = t >> 7;
    float uj = u[lane], vj = v[lane], bj = b2[lane];
    float accM = 0.f, accP = 0.f;
    int stride = gridDim.x * 2;
    for (int d = blockIdx.x * 2 + grp; d < Ntot; d += stride) {
        float2 q = si[d];                  // (s, inv)
        float P = PM[2 * d], M = PM[2 * d + 1];
        float iv = q.y;
        float A = iv * fmaf(iv, fmaxf(q.x, 0.f), P);
        float B = iv * fmaf(iv, fmaxf(-q.x, 0.f), M);
        float r = fmaxf(fmaf(A, uj, fmaf(B, vj, bj)), 0.f);
        if (d < Nm) accM += r; else accP += r;
    }
    sm[0][grp][lane] = accM;
    sm[1][grp][lane] = accP;
    __syncthreads();
    if (t < 128) atomicAdd(&pool[t],       sm[0][0][t] + sm[0][1][t]);
    else         atomicAdd(&pool[t],       sm[1][0][t - 128] + sm[1][1][t - 128]);
}

// ================= fallback path (b1 != 0), guarded =================

__global__ void k_scan_tile(const int* __restrict__ in, int N,
                            int* __restrict__ out, int* __restrict__ tilesums,
                            const int* __restrict__ flags) {
    if (!flags[0]) return;
    __shared__ int sm[256];
    int t = threadIdx.x;
    int g = blockIdx.x * 256 + t;
    int v = (g < N) ? in[g] : 0;
    sm[t] = v;
    __syncthreads();
    for (int off = 1; off < 256; off <<= 1) {
        int x = sm[t];
        int y = (t >= off) ? sm[t - off] : 0;
        __syncthreads();
        sm[t] = x + y;
        __syncthreads();
    }
    int incl = sm[t];
    if (g < N) out[g] = incl - v;
    if (t == 255) tilesums[blockIdx.x] = incl;
}

__global__ void k_scan_sums(int* __restrict__ sums, int B, const int* __restrict__ flags) {
    if (!flags[0]) return;
    __shared__ int sm[1024];
    int t = threadIdx.x;
    int v = (t < B) ? sums[t] : 0;
    sm[t] = v;
    __syncthreads();
    for (int off = 1; off < 1024; off <<= 1) {
        int x = sm[t];
        int y = (t >= off) ? sm[t - off] : 0;
        __syncthreads();
        sm[t] = x + y;
        __syncthreads();
    }
    if (t < B) sums[t] = sm[t] - v;
}

__global__ void k_scan_add(int* __restrict__ rowst, int Ntot,
                           const int* __restrict__ sums, int* __restrict__ cursor,
                           const int* __restrict__ flags) {
    if (!flags[0]) return;
    int g = blockIdx.x * 256 + threadIdx.x;
    if (g < Ntot) {
        int v = rowst[g] + sums[blockIdx.x];
        rowst[g] = v;
        cursor[g] = v;
    }
}

__global__ void k_build(const int* __restrict__ me, const int* __restrict__ pe,
                        int Em, int Ep, int Nm,
                        int* __restrict__ cursor, int* __restrict__ sorted,
                        const int* __restrict__ flags) {
    if (!flags[0]) return;
    int e = blockIdx.x * 256 + threadIdx.x;
    if (e >= Em + Ep) return;
    int s, d;
    if (e < Em) { s = me[e];            d = me[Em + e]; }
    else        { int ee = e - Em; s = pe[ee] + Nm; d = pe[Ep + ee] + Nm; }
    int p = atomicAdd(&cursor[d], 1);
    sorted[p] = s;
}

__global__ __launch_bounds__(256) void k_agg2(
        const int* __restrict__ rowst, const int* __restrict__ hist,
        const float2* __restrict__ si, const int* __restrict__ sorted,
        const float* __restrict__ W1, const float* __restrict__ b1,
        int Ntot, float* __restrict__ agg2, const int* __restrict__ flags) {
    if (!flags[0]) return;
    int lane = threadIdx.x & 63;
    int wv   = (blockIdx.x * 256 + threadIdx.x) >> 6;
    int nW   = gridDim.x * 4;
    float wa = W1[lane],  wb  = W1[lane + 64];
    float ba = b1[lane],  bbv = b1[lane + 64];
    for (int d = wv; d < Ntot; d += nW) {
        int st  = rowst[d];
        int cnt = hist[d];
        float aa = 0.f, ab = 0.f;
        for (int b0 = 0; b0 < cnt; b0 += 64) {
            int take = cnt - b0; if (take > 64) take = 64;
            int l = (lane < take) ? lane : 0;
            int idx = sorted[st + b0 + l];
            float2 sv = si[idx];
            for (int i = 0; i < take; ++i) {
                float s_i = __shfl(sv.x, i);
                float v_i = __shfl(sv.y, i);
                aa = fmaf(v_i, fmaxf(fmaf(s_i, wa, ba ), 0.f), aa);
                ab = fmaf(v_i, fmaxf(fmaf(s_i, wb, bbv), 0.f), ab);
            }
        }
        float2 ps = si[d];
        float oa = fmaxf(fmaf(ps.x, wa, ba ), 0.f);
        float ob = fmaxf(fmaf(ps.x, wb, bbv), 0.f);
        agg2[(size_t)d * 128 + lane]      = ps.y * (aa + ps.y * oa);
        agg2[(size_t)d * 128 + 64 + lane] = ps.y * (ab + ps.y * ob);
    }
}

__global__ __launch_bounds__(256, 2) void k_mm_pool(
        const float* __restrict__ agg2, const float* __restrict__ W2,
        const float* __restrict__ b2, int N, float* __restrict__ pool,
        const int* __restrict__ flags) {
    if (!flags[0]) return;
    __shared__ float sW[128 * 128];
    __shared__ float sR[8 * 128];
    int t = threadIdx.x;
    {
        const float4* srcp = (const float4*)W2;
        float4* dstp = (float4*)sW;
        for (int i = t; i < 128 * 128 / 4; i += 256) dstp[i] = srcp[i];
    }
    __syncthreads();

    int jg = t & 31;
    int rg = t >> 5;
    int j0 = jg * 4;
    int r0 = blockIdx.x * 64 + rg * 8;
    const float4 bbv = *(const float4*)&b2[j0];

    const float* p0 = agg2 + (size_t)min(r0 + 0, N - 1) * 128;
    const float* p1 = agg2 + (size_t)min(r0 + 1, N - 1) * 128;
    const float* p2 = agg2 + (size_t)min(r0 + 2, N - 1) * 128;
    const float* p3 = agg2 + (size_t)min(r0 + 3, N - 1) * 128;
    const float* p4 = agg2 + (size_t)min(r0 + 4, N - 1) * 128;
    const float* p5 = agg2 + (size_t)min(r0 + 5, N - 1) * 128;
    const float* p6 = agg2 + (size_t)min(r0 + 6, N - 1) * 128;
    const float* p7 = agg2 + (size_t)min(r0 + 7, N - 1) * 128;

    float4 acc0 = bbv, acc1 = bbv, acc2 = bbv, acc3 = bbv;
    float4 acc4 = bbv, acc5 = bbv, acc6 = bbv, acc7 = bbv;
    float4 w0, w1, w2, w3;
    float4 xA0, xA1, xA2, xA3, xA4, xA5, xA6, xA7;
    float4 xB0, xB1, xB2, xB3, xB4, xB5, xB6, xB7;

#define LOADA(X, kk) \
    X##0 = *(const float4*)(p0 + (kk)); X##1 = *(const float4*)(p1 + (kk)); \
    X##2 = *(const float4*)(p2 + (kk)); X##3 = *(const float4*)(p3 + (kk)); \
    X##4 = *(const float4*)(p4 + (kk)); X##5 = *(const float4*)(p5 + (kk)); \
    X##6 = *(const float4*)(p6 + (kk)); X##7 = *(const float4*)(p7 + (kk));

#define WLOAD(kk) \
    w0 = *(const float4*)&sW[((kk) + 0) * 128 + j0]; \
    w1 = *(const float4*)&sW[((kk) + 1) * 128 + j0]; \
    w2 = *(const float4*)&sW[((kk) + 2) * 128 + j0]; \
    w3 = *(const float4*)&sW[((kk) + 3) * 128 + j0];

#define FMAROW(acc, av) \
    acc.x = fmaf(av.x, w0.x, acc.x); acc.y = fmaf(av.x, w0.y, acc.y); \
    acc.z = fmaf(av.x, w0.z, acc.z); acc.w = fmaf(av.x, w0.w, acc.w); \
    acc.x = fmaf(av.y, w1.x, acc.x); acc.y = fmaf(av.y, w1.y, acc.y); \
    acc.z = fmaf(av.y, w1.z, acc.z); acc.w = fmaf(av.y, w1.w, acc.w); \
    acc.x = fmaf(av.z, w2.x, acc.x); acc.y = fmaf(av.z, w2.y, acc.y); \
    acc.z = fmaf(av.z, w2.z, acc.z); acc.w = fmaf(av.z, w2.w, acc.w); \
    acc.x = fmaf(av.w, w3.x, acc.x); acc.y = fmaf(av.w, w3.y, acc.y); \
    acc.z = fmaf(av.w, w3.z, acc.z); acc.w = fmaf(av.w, w3.w, acc.w);

#define FMALL(X) \
    FMAROW(acc0, X##0) FMAROW(acc1, X##1) FMAROW(acc2, X##2) FMAROW(acc3, X##3) \
    FMAROW(acc4, X##4) FMAROW(acc5, X##5) FMAROW(acc6, X##6) FMAROW(acc7, X##7)

    LOADA(xA, 0)
    for (int k = 0; k < 128; k += 8) {
        LOADA(xB, k + 4)
        WLOAD(k)
        FMALL(xA)
        if (k + 8 < 128) { LOADA(xA, k + 8) }
        WLOAD(k + 4)
        FMALL(xB)
    }
#undef LOADA
#undef WLOAD
#undef FMAROW
#undef FMALL

    float4 pA = make_float4(0.f, 0.f, 0.f, 0.f);
#define POOLROW(i, acc) \
    if (r0 + i < N) { pA.x += fmaxf(acc.x, 0.f); pA.y += fmaxf(acc.y, 0.f); \
                      pA.z += fmaxf(acc.z, 0.f); pA.w += fmaxf(acc.w, 0.f); }
    POOLROW(0, acc0) POOLROW(1, acc1) POOLROW(2, acc2) POOLROW(3, acc3)
    POOLROW(4, acc4) POOLROW(5, acc5) POOLROW(6, acc6) POOLROW(7, acc7)
#undef POOLROW

    *(float4*)&sR[rg * 128 + j0] = pA;
    __syncthreads();
    if (t < 128) {
        float s = 0.f;
        #pragma unroll
        for (int r = 0; r < 8; ++r) s += sR[r * 128 + t];
        atomicAdd(&pool[t], s);
    }
}

// ---------------- final 257-dim dot ----------------
__global__ void k_final(const float* __restrict__ pool, const float* __restrict__ phys,
                        const float* __restrict__ Wfc, const float* __restrict__ bfc,
                        float* __restrict__ out) {
    __shared__ float sm[256];
    int t = threadIdx.x;
    float acc = pool[t] * Wfc[t];
    if (t == 0) acc += phys[0] * Wfc[256] + bfc[0];
    sm[t] = acc;
    __syncthreads();
    for (int off = 128; off > 0; off >>= 1) {
        if (t < off) sm[t] += sm[t + off];
        __syncthreads();
    }
    if (t == 0) out[0] = sm[0];
}

extern "C" void kernel_launch(void* const* d_in, const int* in_sizes, int n_in,
                              void* d_out, int out_size, void* d_ws, size_t ws_size,
                              hipStream_t stream) {
    const float* mol_x  = (const float*)d_in[0];
    const int*   mol_e  = (const int*)  d_in[1];
    const float* prot_x = (const float*)d_in[2];
    const int*   prot_e = (const int*)  d_in[3];
    const float* phys   = (const float*)d_in[4];
    const float* W1     = (const float*)d_in[5];
    const float* b1     = (const float*)d_in[6];
    const float* W2     = (const float*)d_in[7];
    const float* b2     = (const float*)d_in[8];
    const float* Wfc    = (const float*)d_in[9];
    const float* bfc    = (const float*)d_in[10];
    float* out = (float*)d_out;

    int Nm = in_sizes[0], Em = in_sizes[1] / 2;
    int Np = in_sizes[2], Ep = in_sizes[3] / 2;
    int Ntot = Nm + Np, Etot = Em + Ep;

    char* p = (char*)d_ws;
    auto alloc = [&](size_t bytes) -> char* {
        char* r = p;
        p += (bytes + 255) & ~(size_t)255;
        return r;
    };
    float*  agg2  = (float*) alloc((size_t)Ntot * 128 * 4);   // fallback only
    int*    sorted= (int*)   alloc((size_t)Etot * 4);         // fallback only
    int*    hist  = (int*)   alloc((size_t)Ntot * 4);         // ---- memset region start
    float*  s_acc = (float*) alloc((size_t)Ntot * 4);
    float*  PM    = (float*) alloc((size_t)Ntot * 8);
    float*  pool  = (float*) alloc(256 * 4);                  // ---- memset region end
    int*    rowst = (int*)   alloc((size_t)Ntot * 4);
    int*    cursor= (int*)   alloc((size_t)Ntot * 4);
    int*    tiles = (int*)   alloc(4096);
    float*  xi    = (float*) alloc((size_t)Ntot * 4);
    float2* si    = (float2*)alloc((size_t)Ntot * 8);
    float*  u     = (float*) alloc(128 * 4);
    float*  v     = (float*) alloc(128 * 4);
    int*    flags = (int*)   alloc(256);

    size_t zbytes = (char*)(pool + 256) - (char*)hist;
    hipMemsetAsync(hist, 0, zbytes, stream);                  // hist + s_acc + PM + pool

    int B  = CDIV(Ntot, 256);
    int EB = CDIV(Etot, 256);

    k_flag <<<1, 128, 0, stream>>>(b1, flags);
    k_hist <<<EB, 256, 0, stream>>>(mol_e, prot_e, Em, Ep, Nm, hist);
    k_inv  <<<B, 256, 0, stream>>>(hist, mol_x, prot_x, Nm, Ntot, xi);
    k_push1<<<EB, 256, 0, stream>>>(mol_e, prot_e, Em, Ep, Nm, xi, s_acc);
    k_s    <<<B, 256, 0, stream>>>(hist, s_acc, xi, Ntot, si);

    // fast path (b1 == 0): rank-2 factorized layer-2 + pooled matmul
    k_push2    <<<EB, 256, 0, stream>>>(mol_e, prot_e, Em, Ep, Nm, si, PM, flags);
    k_uv       <<<1, 128, 0, stream>>>(W1, W2, u, v, flags);
    k_pool_fact<<<256, 256, 0, stream>>>(si, PM, u, v, b2, Nm, Ntot, pool, flags);

    // fallback path (b1 != 0): CSR build + gather aggregation + dense matmul/pool
    k_scan_tile<<<B, 256, 0, stream>>>(hist, Ntot, rowst, tiles, flags);
    k_scan_sums<<<1, 1024, 0, stream>>>(tiles, B, flags);
    k_scan_add <<<B, 256, 0, stream>>>(rowst, Ntot, tiles, cursor, flags);
    k_build    <<<EB, 256, 0, stream>>>(mol_e, prot_e, Em, Ep, Nm, cursor, sorted, flags);
    k_agg2     <<<4096, 256, 0, stream>>>(rowst, hist, si, sorted, W1, b1, Ntot, agg2, flags);
    k_mm_pool  <<<CDIV(Nm, 64), 256, 0, stream>>>(agg2, W2, b2, Nm, pool, flags);
    k_mm_pool  <<<CDIV(Np, 64), 256, 0, stream>>>(agg2 + (size_t)Nm * 128, W2, b2,
                                                  Np, pool + 128, flags);

    k_final<<<1, 256, 0, stream>>>(pool, phys, Wfc, bfc, out);
}

// Round 7
// 240.166 us; speedup vs baseline: 10.4056x; 1.9692x over previous
//
#include <hip/hip_runtime.h>

#define CDIV(a,b) (((a)+(b)-1)/(b))

// Combined node ids: mol [0,Nm), prot [Nm,Nm+Np).  Bucket = node >> 12 (4096 nodes/bucket,
// NBKT = CDIV(Ntot,4096) <= 64 for this problem).  Edges are counting-sorted by bucket once
// (k_count -> flat scan -> k_binsort, deterministic positions, coalesced writes); the three
// per-dst accumulations (deg, s_acc, PM) then run over binned edges with LDS-resident
// accumulators + one coalesced atomic flush per bucket-slice.
// Fast path (b1==0): relu(s*w) bilinear split -> rank-2 factorized layer 2.
// Fallback path (b1!=0): round-5 CSR pipeline, guarded by flags[0].

__device__ __forceinline__ void edge_sd(const int* __restrict__ me, const int* __restrict__ pe,
                                        int Em, int Ep, int Nm, int e, int& s, int& d) {
    if (e < Em) { s = me[e];                  d = me[Em + e]; }
    else        { int ee = e - Em; s = pe[ee] + Nm; d = pe[Ep + ee] + Nm; }
}

// ---------------- flag: is b1 nonzero anywhere? ----------------
__global__ void k_flag(const float* __restrict__ b1, int* __restrict__ flags) {
    __shared__ int nz;
    if (threadIdx.x == 0) nz = 0;
    __syncthreads();
    if (threadIdx.x < 128 && b1[threadIdx.x] != 0.f) atomicOr(&nz, 1);
    __syncthreads();
    if (threadIdx.x == 0) flags[0] = nz;
}

// ---------------- bin pass 1: per-(bucket,block) counts ----------------
__global__ __launch_bounds__(256) void k_count(
        const int* __restrict__ me, const int* __restrict__ pe,
        int Em, int Ep, int Nm, int per, int NBIN, int NBKT,
        int* __restrict__ cmat) {
    __shared__ int cnt[64];
    int blk = blockIdx.x, t = threadIdx.x;
    int Etot = Em + Ep;
    int e0 = blk * per;
    int e1 = min(e0 + per, Etot);
    if (t < 64) cnt[t] = 0;
    __syncthreads();
    for (int e = e0 + t; e < e1; e += 256) {
        int s, d; edge_sd(me, pe, Em, Ep, Nm, e, s, d);
        atomicAdd(&cnt[d >> 12], 1);
    }
    __syncthreads();
    if (t < NBKT) cmat[t * NBIN + blk] = cnt[t];
}

// ---------------- flat 2-level exclusive scan (unguarded, for cmat) ----------------
__global__ void k_scan_tile(const int* __restrict__ in, int N,
                            int* __restrict__ out, int* __restrict__ tilesums) {
    __shared__ int sm[256];
    int t = threadIdx.x;
    int g = blockIdx.x * 256 + t;
    int v = (g < N) ? in[g] : 0;
    sm[t] = v;
    __syncthreads();
    for (int off = 1; off < 256; off <<= 1) {
        int x = sm[t];
        int y = (t >= off) ? sm[t - off] : 0;
        __syncthreads();
        sm[t] = x + y;
        __syncthreads();
    }
    int incl = sm[t];
    if (g < N) out[g] = incl - v;
    if (t == 255) tilesums[blockIdx.x] = incl;
}

__global__ void k_scan_sums(int* __restrict__ sums, int B) {
    __shared__ int sm[1024];
    int t = threadIdx.x;
    int v = (t < B) ? sums[t] : 0;
    sm[t] = v;
    __syncthreads();
    for (int off = 1; off < 1024; off <<= 1) {
        int x = sm[t];
        int y = (t >= off) ? sm[t - off] : 0;
        __syncthreads();
        sm[t] = x + y;
        __syncthreads();
    }
    if (t < B) sums[t] = sm[t] - v;
}

__global__ void k_scan_add(int* __restrict__ arr, int N, const int* __restrict__ sums) {
    int g = blockIdx.x * 256 + threadIdx.x;
    if (g < N) arr[g] += sums[blockIdx.x];
}

// ---------------- bin pass 2: in-LDS counting sort + coalesced writeout ----------------
#define BINCAP 2560
__global__ __launch_bounds__(256) void k_binsort(
        const int* __restrict__ me, const int* __restrict__ pe,
        int Em, int Ep, int Nm, int per, int NBIN, int NBKT,
        const int* __restrict__ coff, int* __restrict__ srcb, int* __restrict__ dstb) {
    __shared__ int lsrc[BINCAP], ldst[BINCAP];
    __shared__ unsigned char lbkt[BINCAP];
    __shared__ int cnt[64], cnt2[64], cur[64], base[64];
    int blk = blockIdx.x, t = threadIdx.x;
    int Etot = Em + Ep;
    int e0 = blk * per;
    int e1 = min(e0 + per, Etot);
    int ne = max(e1 - e0, 0);
    if (t < 64) cnt[t] = 0;
    __syncthreads();
    for (int e = e0 + t; e < e1; e += 256) {
        int s, d; edge_sd(me, pe, Em, Ep, Nm, e, s, d);
        atomicAdd(&cnt[d >> 12], 1);
    }
    __syncthreads();
    if (t == 0) {
        int run = 0;
        for (int b = 0; b < NBKT; ++b) { cnt2[b] = run; cur[b] = run; run += cnt[b]; }
    }
    __syncthreads();
    for (int e = e0 + t; e < e1; e += 256) {
        int s, d; edge_sd(me, pe, Em, Ep, Nm, e, s, d);
        int b = d >> 12;
        int p = atomicAdd(&cur[b], 1);
        lsrc[p] = s; ldst[p] = d; lbkt[p] = (unsigned char)b;
    }
    if (t < NBKT) base[t] = coff[t * NBIN + blk];
    __syncthreads();
    for (int i = t; i < ne; i += 256) {
        int b = lbkt[i];
        int g = base[b] + (i - cnt2[b]);
        srcb[g] = lsrc[i];
        dstb[g] = ldst[i];
    }
}

// ---------------- accumulate A: degree histogram ----------------
__global__ __launch_bounds__(256) void k_accA(
        const int* __restrict__ dstb, const int* __restrict__ coff,
        int NBIN, int NBKT, int WPB, int Etot, int Ntot, int* __restrict__ hist) {
    __shared__ int h[4096];
    int b  = blockIdx.x / WPB;
    int sl = blockIdx.x % WPB;
    int t  = threadIdx.x;
    int bs = coff[b * NBIN];
    int be = (b + 1 < NBKT) ? coff[(b + 1) * NBIN] : Etot;
    for (int k = t; k < 4096; k += 256) h[k] = 0;
    __syncthreads();
    for (int i = bs + sl * 256 + t; i < be; i += WPB * 256)
        atomicAdd(&h[dstb[i] & 4095], 1);
    __syncthreads();
    for (int k = t; k < 4096; k += 256) {
        int v = h[k];
        int node = (b << 12) + k;
        if (v && node < Ntot) atomicAdd(&hist[node], v);
    }
}

// ---------------- per-node: xi = x * rsqrt(deg+1) ----------------
__global__ void k_inv(const int* __restrict__ hist,
                      const float* __restrict__ mx, const float* __restrict__ px,
                      int Nm, int Ntot, float* __restrict__ xi) {
    int g = blockIdx.x * 256 + threadIdx.x;
    if (g < Ntot) {
        float x = (g < Nm) ? mx[g] : px[g - Nm];
        xi[g] = x * rsqrtf((float)(hist[g] + 1));
    }
}

// ---------------- accumulate B: s_acc[d] += xi[src] ----------------
__global__ __launch_bounds__(256) void k_accB(
        const int* __restrict__ srcb, const int* __restrict__ dstb,
        const int* __restrict__ coff, const float* __restrict__ xi,
        int NBIN, int NBKT, int WPB, int Etot, int Ntot, float* __restrict__ s_acc) {
    __shared__ float acc[4096];
    int b  = blockIdx.x / WPB;
    int sl = blockIdx.x % WPB;
    int t  = threadIdx.x;
    int bs = coff[b * NBIN];
    int be = (b + 1 < NBKT) ? coff[(b + 1) * NBIN] : Etot;
    for (int k = t; k < 4096; k += 256) acc[k] = 0.f;
    __syncthreads();
    for (int i = bs + sl * 256 + t; i < be; i += WPB * 256) {
        int s = srcb[i], d = dstb[i];
        atomicAdd(&acc[d & 4095], xi[s]);
    }
    __syncthreads();
    for (int k = t; k < 4096; k += 256) {
        float v = acc[k];
        int node = (b << 12) + k;
        if (v != 0.f && node < Ntot) atomicAdd(&s_acc[node], v);
    }
}

// ---------------- layer-1 finalize: si[d] = (inv*(s_acc+xi), inv) ----------------
__global__ void k_s(const int* __restrict__ hist, const float* __restrict__ s_acc,
                    const float* __restrict__ xi, int Ntot, float2* __restrict__ si) {
    int i = blockIdx.x * 256 + threadIdx.x;
    if (i >= Ntot) return;
    float iv = rsqrtf((float)(hist[i] + 1));
    si[i] = make_float2(iv * (s_acc[i] + xi[i]), iv);
}

// ---------------- accumulate C (fast only): P/M sign-split sums ----------------
__global__ __launch_bounds__(256) void k_accC(
        const int* __restrict__ srcb, const int* __restrict__ dstb,
        const int* __restrict__ coff, const float2* __restrict__ si,
        int NBIN, int NBKT, int WPB, int Etot, int Ntot, float* __restrict__ PM,
        const int* __restrict__ flags) {
    if (flags[0]) return;
    __shared__ float pm[8192];
    int b  = blockIdx.x / WPB;
    int sl = blockIdx.x % WPB;
    int t  = threadIdx.x;
    int bs = coff[b * NBIN];
    int be = (b + 1 < NBKT) ? coff[(b + 1) * NBIN] : Etot;
    for (int k = t; k < 8192; k += 256) pm[k] = 0.f;
    __syncthreads();
    for (int i = bs + sl * 256 + t; i < be; i += WPB * 256) {
        int s = srcb[i], d = dstb[i];
        float2 q = si[s];
        float val = q.y * q.x;
        int lo = (d & 4095) * 2;
        if (val > 0.f)      atomicAdd(&pm[lo],     val);
        else if (val < 0.f) atomicAdd(&pm[lo + 1], -val);
    }
    __syncthreads();
    for (int k = t; k < 8192; k += 256) {
        float v = pm[k];
        int node = (b << 12) + (k >> 1);
        if (v != 0.f && node < Ntot) atomicAdd(&PM[2 * node + (k & 1)], v);
    }
}

// ---------------- fast: u = W1+ @ W2, v = W1- @ W2 ----------------
__global__ void k_uv(const float* __restrict__ W1, const float* __restrict__ W2,
                     float* __restrict__ u, float* __restrict__ v,
                     const int* __restrict__ flags) {
    if (flags[0]) return;
    int k = threadIdx.x;
    float au = 0.f, av = 0.f;
    for (int j = 0; j < 128; ++j) {
        float w = W1[j];
        float w2 = W2[j * 128 + k];
        au = fmaf(fmaxf(w, 0.f), w2, au);
        av = fmaf(fmaxf(-w, 0.f), w2, av);
    }
    u[k] = au;
    v[k] = av;
}

// ---------------- fast: pooled output directly from (si, PM) ----------------
__global__ __launch_bounds__(256) void k_pool_fact(
        const float2* __restrict__ si, const float* __restrict__ PM,
        const float* __restrict__ u, const float* __restrict__ v,
        const float* __restrict__ b2, int Nm, int Ntot,
        float* __restrict__ pool, const int* __restrict__ flags) {
    if (flags[0]) return;
    __shared__ float sm[2][2][128];
    int t = threadIdx.x;
    int lane = t & 127;
    int grp  = t >> 7;
    float uj = u[lane], vj = v[lane], bj = b2[lane];
    float accM = 0.f, accP = 0.f;
    int stride = gridDim.x * 2;
    for (int d = blockIdx.x * 2 + grp; d < Ntot; d += stride) {
        float2 q = si[d];
        float P = PM[2 * d], M = PM[2 * d + 1];
        float iv = q.y;
        float A = iv * fmaf(iv, fmaxf(q.x, 0.f), P);
        float B = iv * fmaf(iv, fmaxf(-q.x, 0.f), M);
        float r = fmaxf(fmaf(A, uj, fmaf(B, vj, bj)), 0.f);
        if (d < Nm) accM += r; else accP += r;
    }
    sm[0][grp][lane] = accM;
    sm[1][grp][lane] = accP;
    __syncthreads();
    if (t < 128) atomicAdd(&pool[t], sm[0][0][t] + sm[0][1][t]);
    else         atomicAdd(&pool[t], sm[1][0][t - 128] + sm[1][1][t - 128]);
}

// ================= fallback path (b1 != 0), guarded =================

__global__ void k_scan_tileF(const int* __restrict__ in, int N,
                             int* __restrict__ out, int* __restrict__ tilesums,
                             const int* __restrict__ flags) {
    if (!flags[0]) return;
    __shared__ int sm[256];
    int t = threadIdx.x;
    int g = blockIdx.x * 256 + t;
    int v = (g < N) ? in[g] : 0;
    sm[t] = v;
    __syncthreads();
    for (int off = 1; off < 256; off <<= 1) {
        int x = sm[t];
        int y = (t >= off) ? sm[t - off] : 0;
        __syncthreads();
        sm[t] = x + y;
        __syncthreads();
    }
    int incl = sm[t];
    if (g < N) out[g] = incl - v;
    if (t == 255) tilesums[blockIdx.x] = incl;
}

__global__ void k_scan_sumsF(int* __restrict__ sums, int B, const int* __restrict__ flags) {
    if (!flags[0]) return;
    __shared__ int sm[1024];
    int t = threadIdx.x;
    int v = (t < B) ? sums[t] : 0;
    sm[t] = v;
    __syncthreads();
    for (int off = 1; off < 1024; off <<= 1) {
        int x = sm[t];
        int y = (t >= off) ? sm[t - off] : 0;
        __syncthreads();
        sm[t] = x + y;
        __syncthreads();
    }
    if (t < B) sums[t] = sm[t] - v;
}

__global__ void k_scan_addF(int* __restrict__ rowst, int Ntot,
                            const int* __restrict__ sums, int* __restrict__ cursor,
                            const int* __restrict__ flags) {
    if (!flags[0]) return;
    int g = blockIdx.x * 256 + threadIdx.x;
    if (g < Ntot) {
        int v = rowst[g] + sums[blockIdx.x];
        rowst[g] = v;
        cursor[g] = v;
    }
}

__global__ void k_build(const int* __restrict__ me, const int* __restrict__ pe,
                        int Em, int Ep, int Nm,
                        int* __restrict__ cursor, int* __restrict__ sorted,
                        const int* __restrict__ flags) {
    if (!flags[0]) return;
    int e = blockIdx.x * 256 + threadIdx.x;
    if (e >= Em + Ep) return;
    int s, d; edge_sd(me, pe, Em, Ep, Nm, e, s, d);
    int p = atomicAdd(&cursor[d], 1);
    sorted[p] = s;
}

__global__ __launch_bounds__(256) void k_agg2(
        const int* __restrict__ rowst, const int* __restrict__ hist,
        const float2* __restrict__ si, const int* __restrict__ sorted,
        const float* __restrict__ W1, const float* __restrict__ b1,
        int Ntot, float* __restrict__ agg2, const int* __restrict__ flags) {
    if (!flags[0]) return;
    int lane = threadIdx.x & 63;
    int wv   = (blockIdx.x * 256 + threadIdx.x) >> 6;
    int nW   = gridDim.x * 4;
    float wa = W1[lane],  wb  = W1[lane + 64];
    float ba = b1[lane],  bbv = b1[lane + 64];
    for (int d = wv; d < Ntot; d += nW) {
        int st  = rowst[d];
        int cnt = hist[d];
        float aa = 0.f, ab = 0.f;
        for (int b0 = 0; b0 < cnt; b0 += 64) {
            int take = cnt - b0; if (take > 64) take = 64;
            int l = (lane < take) ? lane : 0;
            int idx = sorted[st + b0 + l];
            float2 sv = si[idx];
            for (int i = 0; i < take; ++i) {
                float s_i = __shfl(sv.x, i);
                float v_i = __shfl(sv.y, i);
                aa = fmaf(v_i, fmaxf(fmaf(s_i, wa, ba ), 0.f), aa);
                ab = fmaf(v_i, fmaxf(fmaf(s_i, wb, bbv), 0.f), ab);
            }
        }
        float2 ps = si[d];
        float oa = fmaxf(fmaf(ps.x, wa, ba ), 0.f);
        float ob = fmaxf(fmaf(ps.x, wb, bbv), 0.f);
        agg2[(size_t)d * 128 + lane]      = ps.y * (aa + ps.y * oa);
        agg2[(size_t)d * 128 + 64 + lane] = ps.y * (ab + ps.y * ob);
    }
}

__global__ __launch_bounds__(256, 2) void k_mm_pool(
        const float* __restrict__ agg2, const float* __restrict__ W2,
        const float* __restrict__ b2, int N, float* __restrict__ pool,
        const int* __restrict__ flags) {
    if (!flags[0]) return;
    __shared__ float sW[128 * 128];
    __shared__ float sR[8 * 128];
    int t = threadIdx.x;
    {
        const float4* srcp = (const float4*)W2;
        float4* dstp = (float4*)sW;
        for (int i = t; i < 128 * 128 / 4; i += 256) dstp[i] = srcp[i];
    }
    __syncthreads();

    int jg = t & 31;
    int rg = t >> 5;
    int j0 = jg * 4;
    int r0 = blockIdx.x * 64 + rg * 8;
    const float4 bbv = *(const float4*)&b2[j0];

    const float* p0 = agg2 + (size_t)min(r0 + 0, N - 1) * 128;
    const float* p1 = agg2 + (size_t)min(r0 + 1, N - 1) * 128;
    const float* p2 = agg2 + (size_t)min(r0 + 2, N - 1) * 128;
    const float* p3 = agg2 + (size_t)min(r0 + 3, N - 1) * 128;
    const float* p4 = agg2 + (size_t)min(r0 + 4, N - 1) * 128;
    const float* p5 = agg2 + (size_t)min(r0 + 5, N - 1) * 128;
    const float* p6 = agg2 + (size_t)min(r0 + 6, N - 1) * 128;
    const float* p7 = agg2 + (size_t)min(r0 + 7, N - 1) * 128;

    float4 acc0 = bbv, acc1 = bbv, acc2 = bbv, acc3 = bbv;
    float4 acc4 = bbv, acc5 = bbv, acc6 = bbv, acc7 = bbv;
    float4 w0, w1, w2, w3;
    float4 xA0, xA1, xA2, xA3, xA4, xA5, xA6, xA7;
    float4 xB0, xB1, xB2, xB3, xB4, xB5, xB6, xB7;

#define LOADA(X, kk) \
    X##0 = *(const float4*)(p0 + (kk)); X##1 = *(const float4*)(p1 + (kk)); \
    X##2 = *(const float4*)(p2 + (kk)); X##3 = *(const float4*)(p3 + (kk)); \
    X##4 = *(const float4*)(p4 + (kk)); X##5 = *(const float4*)(p5 + (kk)); \
    X##6 = *(const float4*)(p6 + (kk)); X##7 = *(const float4*)(p7 + (kk));

#define WLOAD(kk) \
    w0 = *(const float4*)&sW[((kk) + 0) * 128 + j0]; \
    w1 = *(const float4*)&sW[((kk) + 1) * 128 + j0]; \
    w2 = *(const float4*)&sW[((kk) + 2) * 128 + j0]; \
    w3 = *(const float4*)&sW[((kk) + 3) * 128 + j0];

#define FMAROW(acc, av) \
    acc.x = fmaf(av.x, w0.x, acc.x); acc.y = fmaf(av.x, w0.y, acc.y); \
    acc.z = fmaf(av.x, w0.z, acc.z); acc.w = fmaf(av.x, w0.w, acc.w); \
    acc.x = fmaf(av.y, w1.x, acc.x); acc.y = fmaf(av.y, w1.y, acc.y); \
    acc.z = fmaf(av.y, w1.z, acc.z); acc.w = fmaf(av.y, w1.w, acc.w); \
    acc.x = fmaf(av.z, w2.x, acc.x); acc.y = fmaf(av.z, w2.y, acc.y); \
    acc.z = fmaf(av.z, w2.z, acc.z); acc.w = fmaf(av.z, w2.w, acc.w); \
    acc.x = fmaf(av.w, w3.x, acc.x); acc.y = fmaf(av.w, w3.y, acc.y); \
    acc.z = fmaf(av.w, w3.z, acc.z); acc.w = fmaf(av.w, w3.w, acc.w);

#define FMALL(X) \
    FMAROW(acc0, X##0) FMAROW(acc1, X##1) FMAROW(acc2, X##2) FMAROW(acc3, X##3) \
    FMAROW(acc4, X##4) FMAROW(acc5, X##5) FMAROW(acc6, X##6) FMAROW(acc7, X##7)

    LOADA(xA, 0)
    for (int k = 0; k < 128; k += 8) {
        LOADA(xB, k + 4)
        WLOAD(k)
        FMALL(xA)
        if (k + 8 < 128) { LOADA(xA, k + 8) }
        WLOAD(k + 4)
        FMALL(xB)
    }
#undef LOADA
#undef WLOAD
#undef FMAROW
#undef FMALL

    float4 pA = make_float4(0.f, 0.f, 0.f, 0.f);
#define POOLROW(i, acc) \
    if (r0 + i < N) { pA.x += fmaxf(acc.x, 0.f); pA.y += fmaxf(acc.y, 0.f); \
                      pA.z += fmaxf(acc.z, 0.f); pA.w += fmaxf(acc.w, 0.f); }
    POOLROW(0, acc0) POOLROW(1, acc1) POOLROW(2, acc2) POOLROW(3, acc3)
    POOLROW(4, acc4) POOLROW(5, acc5) POOLROW(6, acc6) POOLROW(7, acc7)
#undef POOLROW

    *(float4*)&sR[rg * 128 + j0] = pA;
    __syncthreads();
    if (t < 128) {
        float s = 0.f;
        #pragma unroll
        for (int r = 0; r < 8; ++r) s += sR[r * 128 + t];
        atomicAdd(&pool[t], s);
    }
}

// ---------------- final 257-dim dot ----------------
__global__ void k_final(const float* __restrict__ pool, const float* __restrict__ phys,
                        const float* __restrict__ Wfc, const float* __restrict__ bfc,
                        float* __restrict__ out) {
    __shared__ float sm[256];
    int t = threadIdx.x;
    float acc = pool[t] * Wfc[t];
    if (t == 0) acc += phys[0] * Wfc[256] + bfc[0];
    sm[t] = acc;
    __syncthreads();
    for (int off = 128; off > 0; off >>= 1) {
        if (t < off) sm[t] += sm[t + off];
        __syncthreads();
    }
    if (t == 0) out[0] = sm[0];
}

extern "C" void kernel_launch(void* const* d_in, const int* in_sizes, int n_in,
                              void* d_out, int out_size, void* d_ws, size_t ws_size,
                              hipStream_t stream) {
    const float* mol_x  = (const float*)d_in[0];
    const int*   mol_e  = (const int*)  d_in[1];
    const float* prot_x = (const float*)d_in[2];
    const int*   prot_e = (const int*)  d_in[3];
    const float* phys   = (const float*)d_in[4];
    const float* W1     = (const float*)d_in[5];
    const float* b1     = (const float*)d_in[6];
    const float* W2     = (const float*)d_in[7];
    const float* b2     = (const float*)d_in[8];
    const float* Wfc    = (const float*)d_in[9];
    const float* bfc    = (const float*)d_in[10];
    float* out = (float*)d_out;

    int Nm = in_sizes[0], Em = in_sizes[1] / 2;
    int Np = in_sizes[2], Ep = in_sizes[3] / 2;
    int Ntot = Nm + Np, Etot = Em + Ep;

    // binning geometry: bucket = node >> 12; per-block edge chunk <= BINCAP
    int NBKT = CDIV(Ntot, 4096);               // 37 for this problem (must be <= 64)
    int NBIN = CDIV(Etot, 2304);               // blocks for count/binsort
    int per  = CDIV(Etot, NBIN);               // <= 2304 <= BINCAP
    int M    = NBKT * NBIN;                    // count-matrix elements

    char* p = (char*)d_ws;
    auto alloc = [&](size_t bytes) -> char* {
        char* r = p;
        p += (bytes + 255) & ~(size_t)255;
        return r;
    };
    float*  agg2  = (float*) alloc((size_t)Ntot * 128 * 4);   // fallback only
    int*    sorted= (int*)   alloc((size_t)Etot * 4);         // fallback only
    int*    srcb  = (int*)   alloc((size_t)Etot * 4);
    int*    dstb  = (int*)   alloc((size_t)Etot * 4);
    int*    cmat  = (int*)   alloc((size_t)M * 4);
    int*    coff  = (int*)   alloc((size_t)M * 4);
    int*    tilesA= (int*)   alloc(4096);
    int*    tilesB= (int*)   alloc(4096);
    int*    hist  = (int*)   alloc((size_t)Ntot * 4);         // ---- memset region start
    float*  s_acc = (float*) alloc((size_t)Ntot * 4);
    float*  PM    = (float*) alloc((size_t)Ntot * 8);
    float*  pool  = (float*) alloc(256 * 4);                  // ---- memset region end
    int*    rowst = (int*)   alloc((size_t)Ntot * 4);         // fallback
    int*    cursor= (int*)   alloc((size_t)Ntot * 4);         // fallback
    float*  xi    = (float*) alloc((size_t)Ntot * 4);
    float2* si    = (float2*)alloc((size_t)Ntot * 8);
    float*  u     = (float*) alloc(128 * 4);
    float*  v     = (float*) alloc(128 * 4);
    int*    flags = (int*)   alloc(256);

    size_t zbytes = (char*)(pool + 256) - (char*)hist;
    hipMemsetAsync(hist, 0, zbytes, stream);                  // hist + s_acc + PM + pool

    int B   = CDIV(Ntot, 256);
    int B2  = CDIV(M, 256);
    const int WPB_A = 32, WPB_B = 32, WPB_C = 16;

    k_flag    <<<1, 128, 0, stream>>>(b1, flags);
    // ---- bin edges by dst bucket (deterministic counting sort, coalesced writes) ----
    k_count   <<<NBIN, 256, 0, stream>>>(mol_e, prot_e, Em, Ep, Nm, per, NBIN, NBKT, cmat);
    k_scan_tile<<<B2, 256, 0, stream>>>(cmat, M, coff, tilesA);
    k_scan_sums<<<1, 1024, 0, stream>>>(tilesA, B2);
    k_scan_add <<<B2, 256, 0, stream>>>(coff, M, tilesA);
    k_binsort <<<NBIN, 256, 0, stream>>>(mol_e, prot_e, Em, Ep, Nm, per, NBIN, NBKT,
                                         coff, srcb, dstb);
    // ---- LDS-resident accumulations over binned edges ----
    k_accA<<<NBKT * WPB_A, 256, 0, stream>>>(dstb, coff, NBIN, NBKT, WPB_A, Etot, Ntot, hist);
    k_inv <<<B, 256, 0, stream>>>(hist, mol_x, prot_x, Nm, Ntot, xi);
    k_accB<<<NBKT * WPB_B, 256, 0, stream>>>(srcb, dstb, coff, xi,
                                             NBIN, NBKT, WPB_B, Etot, Ntot, s_acc);
    k_s   <<<B, 256, 0, stream>>>(hist, s_acc, xi, Ntot, si);
    k_accC<<<NBKT * WPB_C, 256, 0, stream>>>(srcb, dstb, coff, si,
                                             NBIN, NBKT, WPB_C, Etot, Ntot, PM, flags);
    // ---- fast-path epilogue ----
    k_uv       <<<1, 128, 0, stream>>>(W1, W2, u, v, flags);
    k_pool_fact<<<256, 256, 0, stream>>>(si, PM, u, v, b2, Nm, Ntot, pool, flags);
    // ---- fallback path (b1 != 0) ----
    k_scan_tileF<<<B, 256, 0, stream>>>(hist, Ntot, rowst, tilesB, flags);
    k_scan_sumsF<<<1, 1024, 0, stream>>>(tilesB, B, flags);
    k_scan_addF <<<B, 256, 0, stream>>>(rowst, Ntot, tilesB, cursor, flags);
    k_build     <<<CDIV(Etot, 256), 256, 0, stream>>>(mol_e, prot_e, Em, Ep, Nm,
                                                      cursor, sorted, flags);
    k_agg2      <<<4096, 256, 0, stream>>>(rowst, hist, si, sorted, W1, b1, Ntot, agg2, flags);
    k_mm_pool   <<<CDIV(Nm, 64), 256, 0, stream>>>(agg2, W2, b2, Nm, pool, flags);
    k_mm_pool   <<<CDIV(Np, 64), 256, 0, stream>>>(agg2 + (size_t)Nm * 128, W2, b2,
                                                   Np, pool + 128, flags);

    k_final<<<1, 256, 0, stream>>>(pool, phys, Wfc, bfc, out);
}

// Round 8
// 172.131 us; speedup vs baseline: 14.5183x; 1.3952x over previous
//
#include <hip/hip_runtime.h>

#define CDIV(a,b) (((a)+(b)-1)/(b))

// Combined node ids: mol [0,Nm), prot [Nm,Nm+Np).  Bucket = node >> 12 (4096 nodes/bucket).
// Edges counting-sorted by bucket once (k_count -> scan -> k_binsort, coalesced writes);
// per-dst accumulations (deg, s_acc, PM) run over binned edges with LDS-resident
// accumulators + coalesced atomic flush.  Fast path (b1==0): relu bilinear sign-split ->
// rank-2 factorized layer 2 (k_uv + k_pool_fact).  Fallback (b1!=0): CSR pipeline.

__device__ __forceinline__ void edge_sd(const int* __restrict__ me, const int* __restrict__ pe,
                                        int Em, int Ep, int Nm, int e, int& s, int& d) {
    if (e < Em) { s = me[e];                  d = me[Em + e]; }
    else        { int ee = e - Em; s = pe[ee] + Nm; d = pe[Ep + ee] + Nm; }
}

// ---------------- flag: is b1 nonzero anywhere? ----------------
__global__ void k_flag(const float* __restrict__ b1, int* __restrict__ flags) {
    __shared__ int nz;
    if (threadIdx.x == 0) nz = 0;
    __syncthreads();
    if (threadIdx.x < 128 && b1[threadIdx.x] != 0.f) atomicOr(&nz, 1);
    __syncthreads();
    if (threadIdx.x == 0) flags[0] = nz;
}

// ---------------- bin pass 1: per-(bucket,block) counts ----------------
__global__ __launch_bounds__(256) void k_count(
        const int* __restrict__ me, const int* __restrict__ pe,
        int Em, int Ep, int Nm, int per, int NBIN, int NBKT,
        int* __restrict__ cmat) {
    __shared__ int cnt[64];
    int blk = blockIdx.x, t = threadIdx.x;
    int Etot = Em + Ep;
    int e0 = blk * per;
    int e1 = min(e0 + per, Etot);
    if (t < 64) cnt[t] = 0;
    __syncthreads();
    for (int e = e0 + t; e < e1; e += 256) {
        int s, d; edge_sd(me, pe, Em, Ep, Nm, e, s, d);
        atomicAdd(&cnt[d >> 12], 1);
    }
    __syncthreads();
    if (t < NBKT) cmat[t * NBIN + blk] = cnt[t];
}

// ---------------- flat 2-level exclusive scan ----------------
__global__ void k_scan_tile(const int* __restrict__ in, int N,
                            int* __restrict__ out, int* __restrict__ tilesums) {
    __shared__ int sm[256];
    int t = threadIdx.x;
    int g = blockIdx.x * 256 + t;
    int v = (g < N) ? in[g] : 0;
    sm[t] = v;
    __syncthreads();
    for (int off = 1; off < 256; off <<= 1) {
        int x = sm[t];
        int y = (t >= off) ? sm[t - off] : 0;
        __syncthreads();
        sm[t] = x + y;
        __syncthreads();
    }
    int incl = sm[t];
    if (g < N) out[g] = incl - v;
    if (t == 255) tilesums[blockIdx.x] = incl;
}

__global__ void k_scan_sums(int* __restrict__ sums, int B) {
    __shared__ int sm[1024];
    int t = threadIdx.x;
    int v = (t < B) ? sums[t] : 0;
    sm[t] = v;
    __syncthreads();
    for (int off = 1; off < 1024; off <<= 1) {
        int x = sm[t];
        int y = (t >= off) ? sm[t - off] : 0;
        __syncthreads();
        sm[t] = x + y;
        __syncthreads();
    }
    if (t < B) sums[t] = sm[t] - v;
}

__global__ void k_scan_add(int* __restrict__ arr, int N, const int* __restrict__ sums) {
    int g = blockIdx.x * 256 + threadIdx.x;
    if (g < N) arr[g] += sums[blockIdx.x];
}

// ---------------- bin pass 2: in-LDS counting sort + coalesced writeout ----------------
#define BINCAP 2560
__global__ __launch_bounds__(256) void k_binsort(
        const int* __restrict__ me, const int* __restrict__ pe,
        int Em, int Ep, int Nm, int per, int NBIN, int NBKT,
        const int* __restrict__ coff, int* __restrict__ srcb, int* __restrict__ dstb) {
    __shared__ int lsrc[BINCAP], ldst[BINCAP];
    __shared__ unsigned char lbkt[BINCAP];
    __shared__ int cnt[64], cnt2[64], cur[64], base[64];
    int blk = blockIdx.x, t = threadIdx.x;
    int Etot = Em + Ep;
    int e0 = blk * per;
    int e1 = min(e0 + per, Etot);
    int ne = max(e1 - e0, 0);
    if (t < 64) cnt[t] = 0;
    __syncthreads();
    for (int e = e0 + t; e < e1; e += 256) {
        int s, d; edge_sd(me, pe, Em, Ep, Nm, e, s, d);
        atomicAdd(&cnt[d >> 12], 1);
    }
    __syncthreads();
    if (t == 0) {
        int run = 0;
        for (int b = 0; b < NBKT; ++b) { cnt2[b] = run; cur[b] = run; run += cnt[b]; }
    }
    __syncthreads();
    for (int e = e0 + t; e < e1; e += 256) {
        int s, d; edge_sd(me, pe, Em, Ep, Nm, e, s, d);
        int b = d >> 12;
        int p = atomicAdd(&cur[b], 1);
        lsrc[p] = s; ldst[p] = d; lbkt[p] = (unsigned char)b;
    }
    if (t < NBKT) base[t] = coff[t * NBIN + blk];
    __syncthreads();
    for (int i = t; i < ne; i += 256) {
        int b = lbkt[i];
        int g = base[b] + (i - cnt2[b]);
        srcb[g] = lsrc[i];
        dstb[g] = ldst[i];
    }
}

// ---------------- accumulate A: degree histogram ----------------
__global__ __launch_bounds__(256) void k_accA(
        const int* __restrict__ dstb, const int* __restrict__ coff,
        int NBIN, int NBKT, int WPB, int Etot, int Ntot, int* __restrict__ hist) {
    __shared__ int h[4096];
    int b  = blockIdx.x / WPB;
    int sl = blockIdx.x % WPB;
    int t  = threadIdx.x;
    int bs = coff[b * NBIN];
    int be = (b + 1 < NBKT) ? coff[(b + 1) * NBIN] : Etot;
    for (int k = t; k < 4096; k += 256) h[k] = 0;
    __syncthreads();
    for (int i = bs + sl * 256 + t; i < be; i += WPB * 256)
        atomicAdd(&h[dstb[i] & 4095], 1);
    __syncthreads();
    for (int k = t; k < 4096; k += 256) {
        int v = h[k];
        int node = (b << 12) + k;
        if (v && node < Ntot) atomicAdd(&hist[node], v);
    }
}

// ---------------- per-node: xi = x * rsqrt(deg+1) ----------------
__global__ void k_inv(const int* __restrict__ hist,
                      const float* __restrict__ mx, const float* __restrict__ px,
                      int Nm, int Ntot, float* __restrict__ xi) {
    int g = blockIdx.x * 256 + threadIdx.x;
    if (g < Ntot) {
        float x = (g < Nm) ? mx[g] : px[g - Nm];
        xi[g] = x * rsqrtf((float)(hist[g] + 1));
    }
}

// ---------------- accumulate B: s_acc[d] += xi[src] ----------------
__global__ __launch_bounds__(256) void k_accB(
        const int* __restrict__ srcb, const int* __restrict__ dstb,
        const int* __restrict__ coff, const float* __restrict__ xi,
        int NBIN, int NBKT, int WPB, int Etot, int Ntot, float* __restrict__ s_acc) {
    __shared__ float acc[4096];
    int b  = blockIdx.x / WPB;
    int sl = blockIdx.x % WPB;
    int t  = threadIdx.x;
    int bs = coff[b * NBIN];
    int be = (b + 1 < NBKT) ? coff[(b + 1) * NBIN] : Etot;
    for (int k = t; k < 4096; k += 256) acc[k] = 0.f;
    __syncthreads();
    for (int i = bs + sl * 256 + t; i < be; i += WPB * 256) {
        int s = srcb[i], d = dstb[i];
        atomicAdd(&acc[d & 4095], xi[s]);
    }
    __syncthreads();
    for (int k = t; k < 4096; k += 256) {
        float v = acc[k];
        int node = (b << 12) + k;
        if (v != 0.f && node < Ntot) atomicAdd(&s_acc[node], v);
    }
}

// ---------------- layer-1 finalize: si[d] = (inv*(s_acc+xi), inv) ----------------
__global__ void k_s(const int* __restrict__ hist, const float* __restrict__ s_acc,
                    const float* __restrict__ xi, int Ntot, float2* __restrict__ si) {
    int i = blockIdx.x * 256 + threadIdx.x;
    if (i >= Ntot) return;
    float iv = rsqrtf((float)(hist[i] + 1));
    si[i] = make_float2(iv * (s_acc[i] + xi[i]), iv);
}

// ---------------- accumulate C (fast only): P/M sign-split sums ----------------
__global__ __launch_bounds__(256) void k_accC(
        const int* __restrict__ srcb, const int* __restrict__ dstb,
        const int* __restrict__ coff, const float2* __restrict__ si,
        int NBIN, int NBKT, int WPB, int Etot, int Ntot, float* __restrict__ PM,
        const int* __restrict__ flags) {
    if (flags[0]) return;
    __shared__ float pm[8192];
    int b  = blockIdx.x / WPB;
    int sl = blockIdx.x % WPB;
    int t  = threadIdx.x;
    int bs = coff[b * NBIN];
    int be = (b + 1 < NBKT) ? coff[(b + 1) * NBIN] : Etot;
    for (int k = t; k < 8192; k += 256) pm[k] = 0.f;
    __syncthreads();
    for (int i = bs + sl * 256 + t; i < be; i += WPB * 256) {
        int s = srcb[i], d = dstb[i];
        float2 q = si[s];
        float val = q.y * q.x;
        int lo = (d & 4095) * 2;
        if (val > 0.f)      atomicAdd(&pm[lo],     val);
        else if (val < 0.f) atomicAdd(&pm[lo + 1], -val);
    }
    __syncthreads();
    for (int k = t; k < 8192; k += 256) {
        float v = pm[k];
        int node = (b << 12) + (k >> 1);
        if (v != 0.f && node < Ntot) atomicAdd(&PM[2 * node + (k & 1)], v);
    }
}

// ---------------- fast: u = W1+ @ W2, v = W1- @ W2 ----------------
__global__ void k_uv(const float* __restrict__ W1, const float* __restrict__ W2,
                     float* __restrict__ u, float* __restrict__ v,
                     const int* __restrict__ flags) {
    if (flags[0]) return;
    int k = threadIdx.x;
    float au = 0.f, av = 0.f;
    for (int j = 0; j < 128; ++j) {
        float w = W1[j];
        float w2 = W2[j * 128 + k];
        au = fmaf(fmaxf(w, 0.f), w2, au);
        av = fmaf(fmaxf(-w, 0.f), w2, av);
    }
    u[k] = au;
    v[k] = av;
}

// ---------------- fast: pooled output, tile-transposed (coalesced loads + LDS) ----------
// Per 128-node tile: lanes coalesce-load si/PM for 128 DIFFERENT nodes, compute A,B,
// park in LDS; then lane k (feature) runs the inner loop on LDS broadcast reads.
// pool_k += sum_d relu(A_d*u_k + B_d*v_k + b_k) over [base, base+cnt).
__global__ __launch_bounds__(256) void k_pool_fact(
        const float2* __restrict__ si, const float* __restrict__ PM,
        const float* __restrict__ u, const float* __restrict__ v,
        const float* __restrict__ b2, int base, int cnt,
        float* __restrict__ poolOut, const int* __restrict__ flags) {
    if (flags[0]) return;
    __shared__ float sA[2][128], sB[2][128], sR[2][128];
    int t = threadIdx.x;
    int k = t & 127;
    int grp = t >> 7;
    float uk = u[k], vk = v[k], bk = b2[k];
    float acc = 0.f;
    int ntile = (cnt + 127) >> 7;
    for (int tb = blockIdx.x * 2; tb < ntile; tb += gridDim.x * 2) {
        int tile = tb + grp;                          // grp1 may be out of range (nn=0)
        int d0 = base + tile * 128;
        int nn = (tile < ntile) ? min(128, base + cnt - d0) : 0;
        float A = 0.f, B = 0.f;
        if (k < nn) {
            float2 q  = si[d0 + k];                   // coalesced
            float2 pm = *(const float2*)&PM[2 * (d0 + k)];
            float iv = q.y;
            A = iv * fmaf(iv, fmaxf(q.x, 0.f), pm.x);
            B = iv * fmaf(iv, fmaxf(-q.x, 0.f), pm.y);
        }
        __syncthreads();                              // previous tile's reads done
        sA[grp][k] = A;
        sB[grp][k] = B;
        __syncthreads();
        #pragma unroll 8
        for (int i = 0; i < nn; ++i)
            acc += fmaxf(fmaf(sA[grp][i], uk, fmaf(sB[grp][i], vk, bk)), 0.f);
    }
    __syncthreads();
    sR[grp][k] = acc;
    __syncthreads();
    if (t < 128) atomicAdd(&poolOut[t], sR[0][t] + sR[1][t]);
}

// ================= fallback path (b1 != 0), guarded =================

__global__ void k_scan_tileF(const int* __restrict__ in, int N,
                             int* __restrict__ out, int* __restrict__ tilesums,
                             const int* __restrict__ flags) {
    if (!flags[0]) return;
    __shared__ int sm[256];
    int t = threadIdx.x;
    int g = blockIdx.x * 256 + t;
    int v = (g < N) ? in[g] : 0;
    sm[t] = v;
    __syncthreads();
    for (int off = 1; off < 256; off <<= 1) {
        int x = sm[t];
        int y = (t >= off) ? sm[t - off] : 0;
        __syncthreads();
        sm[t] = x + y;
        __syncthreads();
    }
    int incl = sm[t];
    if (g < N) out[g] = incl - v;
    if (t == 255) tilesums[blockIdx.x] = incl;
}

__global__ void k_scan_sumsF(int* __restrict__ sums, int B, const int* __restrict__ flags) {
    if (!flags[0]) return;
    __shared__ int sm[1024];
    int t = threadIdx.x;
    int v = (t < B) ? sums[t] : 0;
    sm[t] = v;
    __syncthreads();
    for (int off = 1; off < 1024; off <<= 1) {
        int x = sm[t];
        int y = (t >= off) ? sm[t - off] : 0;
        __syncthreads();
        sm[t] = x + y;
        __syncthreads();
    }
    if (t < B) sums[t] = sm[t] - v;
}

__global__ void k_scan_addF(int* __restrict__ rowst, int Ntot,
                            const int* __restrict__ sums, int* __restrict__ cursor,
                            const int* __restrict__ flags) {
    if (!flags[0]) return;
    int g = blockIdx.x * 256 + threadIdx.x;
    if (g < Ntot) {
        int v = rowst[g] + sums[blockIdx.x];
        rowst[g] = v;
        cursor[g] = v;
    }
}

__global__ void k_build(const int* __restrict__ me, const int* __restrict__ pe,
                        int Em, int Ep, int Nm,
                        int* __restrict__ cursor, int* __restrict__ sorted,
                        const int* __restrict__ flags) {
    if (!flags[0]) return;
    int e = blockIdx.x * 256 + threadIdx.x;
    if (e >= Em + Ep) return;
    int s, d; edge_sd(me, pe, Em, Ep, Nm, e, s, d);
    int p = atomicAdd(&cursor[d], 1);
    sorted[p] = s;
}

__global__ __launch_bounds__(256) void k_agg2(
        const int* __restrict__ rowst, const int* __restrict__ hist,
        const float2* __restrict__ si, const int* __restrict__ sorted,
        const float* __restrict__ W1, const float* __restrict__ b1,
        int Ntot, float* __restrict__ agg2, const int* __restrict__ flags) {
    if (!flags[0]) return;
    int lane = threadIdx.x & 63;
    int wv   = (blockIdx.x * 256 + threadIdx.x) >> 6;
    int nW   = gridDim.x * 4;
    float wa = W1[lane],  wb  = W1[lane + 64];
    float ba = b1[lane],  bbv = b1[lane + 64];
    for (int d = wv; d < Ntot; d += nW) {
        int st  = rowst[d];
        int cnt = hist[d];
        float aa = 0.f, ab = 0.f;
        for (int b0 = 0; b0 < cnt; b0 += 64) {
            int take = cnt - b0; if (take > 64) take = 64;
            int l = (lane < take) ? lane : 0;
            int idx = sorted[st + b0 + l];
            float2 sv = si[idx];
            for (int i = 0; i < take; ++i) {
                float s_i = __shfl(sv.x, i);
                float v_i = __shfl(sv.y, i);
                aa = fmaf(v_i, fmaxf(fmaf(s_i, wa, ba ), 0.f), aa);
                ab = fmaf(v_i, fmaxf(fmaf(s_i, wb, bbv), 0.f), ab);
            }
        }
        float2 ps = si[d];
        float oa = fmaxf(fmaf(ps.x, wa, ba ), 0.f);
        float ob = fmaxf(fmaf(ps.x, wb, bbv), 0.f);
        agg2[(size_t)d * 128 + lane]      = ps.y * (aa + ps.y * oa);
        agg2[(size_t)d * 128 + 64 + lane] = ps.y * (ab + ps.y * ob);
    }
}

__global__ __launch_bounds__(256, 2) void k_mm_pool(
        const float* __restrict__ agg2, const float* __restrict__ W2,
        const float* __restrict__ b2, int N, float* __restrict__ pool,
        const int* __restrict__ flags) {
    if (!flags[0]) return;
    __shared__ float sW[128 * 128];
    __shared__ float sR[8 * 128];
    int t = threadIdx.x;
    {
        const float4* srcp = (const float4*)W2;
        float4* dstp = (float4*)sW;
        for (int i = t; i < 128 * 128 / 4; i += 256) dstp[i] = srcp[i];
    }
    __syncthreads();

    int jg = t & 31;
    int rg = t >> 5;
    int j0 = jg * 4;
    int r0 = blockIdx.x * 64 + rg * 8;
    const float4 bbv = *(const float4*)&b2[j0];

    const float* p0 = agg2 + (size_t)min(r0 + 0, N - 1) * 128;
    const float* p1 = agg2 + (size_t)min(r0 + 1, N - 1) * 128;
    const float* p2 = agg2 + (size_t)min(r0 + 2, N - 1) * 128;
    const float* p3 = agg2 + (size_t)min(r0 + 3, N - 1) * 128;
    const float* p4 = agg2 + (size_t)min(r0 + 4, N - 1) * 128;
    const float* p5 = agg2 + (size_t)min(r0 + 5, N - 1) * 128;
    const float* p6 = agg2 + (size_t)min(r0 + 6, N - 1) * 128;
    const float* p7 = agg2 + (size_t)min(r0 + 7, N - 1) * 128;

    float4 acc0 = bbv, acc1 = bbv, acc2 = bbv, acc3 = bbv;
    float4 acc4 = bbv, acc5 = bbv, acc6 = bbv, acc7 = bbv;
    float4 w0, w1, w2, w3;
    float4 xA0, xA1, xA2, xA3, xA4, xA5, xA6, xA7;
    float4 xB0, xB1, xB2, xB3, xB4, xB5, xB6, xB7;

#define LOADA(X, kk) \
    X##0 = *(const float4*)(p0 + (kk)); X##1 = *(const float4*)(p1 + (kk)); \
    X##2 = *(const float4*)(p2 + (kk)); X##3 = *(const float4*)(p3 + (kk)); \
    X##4 = *(const float4*)(p4 + (kk)); X##5 = *(const float4*)(p5 + (kk)); \
    X##6 = *(const float4*)(p6 + (kk)); X##7 = *(const float4*)(p7 + (kk));

#define WLOAD(kk) \
    w0 = *(const float4*)&sW[((kk) + 0) * 128 + j0]; \
    w1 = *(const float4*)&sW[((kk) + 1) * 128 + j0]; \
    w2 = *(const float4*)&sW[((kk) + 2) * 128 + j0]; \
    w3 = *(const float4*)&sW[((kk) + 3) * 128 + j0];

#define FMAROW(acc, av) \
    acc.x = fmaf(av.x, w0.x, acc.x); acc.y = fmaf(av.x, w0.y, acc.y); \
    acc.z = fmaf(av.x, w0.z, acc.z); acc.w = fmaf(av.x, w0.w, acc.w); \
    acc.x = fmaf(av.y, w1.x, acc.x); acc.y = fmaf(av.y, w1.y, acc.y); \
    acc.z = fmaf(av.y, w1.z, acc.z); acc.w = fmaf(av.y, w1.w, acc.w); \
    acc.x = fmaf(av.z, w2.x, acc.x); acc.y = fmaf(av.z, w2.y, acc.y); \
    acc.z = fmaf(av.z, w2.z, acc.z); acc.w = fmaf(av.z, w2.w, acc.w); \
    acc.x = fmaf(av.w, w3.x, acc.x); acc.y = fmaf(av.w, w3.y, acc.y); \
    acc.z = fmaf(av.w, w3.z, acc.z); acc.w = fmaf(av.w, w3.w, acc.w);

#define FMALL(X) \
    FMAROW(acc0, X##0) FMAROW(acc1, X##1) FMAROW(acc2, X##2) FMAROW(acc3, X##3) \
    FMAROW(acc4, X##4) FMAROW(acc5, X##5) FMAROW(acc6, X##6) FMAROW(acc7, X##7)

    LOADA(xA, 0)
    for (int k = 0; k < 128; k += 8) {
        LOADA(xB, k + 4)
        WLOAD(k)
        FMALL(xA)
        if (k + 8 < 128) { LOADA(xA, k + 8) }
        WLOAD(k + 4)
        FMALL(xB)
    }
#undef LOADA
#undef WLOAD
#undef FMAROW
#undef FMALL

    float4 pA = make_float4(0.f, 0.f, 0.f, 0.f);
#define POOLROW(i, acc) \
    if (r0 + i < N) { pA.x += fmaxf(acc.x, 0.f); pA.y += fmaxf(acc.y, 0.f); \
                      pA.z += fmaxf(acc.z, 0.f); pA.w += fmaxf(acc.w, 0.f); }
    POOLROW(0, acc0) POOLROW(1, acc1) POOLROW(2, acc2) POOLROW(3, acc3)
    POOLROW(4, acc4) POOLROW(5, acc5) POOLROW(6, acc6) POOLROW(7, acc7)
#undef POOLROW

    *(float4*)&sR[rg * 128 + j0] = pA;
    __syncthreads();
    if (t < 128) {
        float s = 0.f;
        #pragma unroll
        for (int r = 0; r < 8; ++r) s += sR[r * 128 + t];
        atomicAdd(&pool[t], s);
    }
}

// ---------------- final 257-dim dot ----------------
__global__ void k_final(const float* __restrict__ pool, const float* __restrict__ phys,
                        const float* __restrict__ Wfc, const float* __restrict__ bfc,
                        float* __restrict__ out) {
    __shared__ float sm[256];
    int t = threadIdx.x;
    float acc = pool[t] * Wfc[t];
    if (t == 0) acc += phys[0] * Wfc[256] + bfc[0];
    sm[t] = acc;
    __syncthreads();
    for (int off = 128; off > 0; off >>= 1) {
        if (t < off) sm[t] += sm[t + off];
        __syncthreads();
    }
    if (t == 0) out[0] = sm[0];
}

extern "C" void kernel_launch(void* const* d_in, const int* in_sizes, int n_in,
                              void* d_out, int out_size, void* d_ws, size_t ws_size,
                              hipStream_t stream) {
    const float* mol_x  = (const float*)d_in[0];
    const int*   mol_e  = (const int*)  d_in[1];
    const float* prot_x = (const float*)d_in[2];
    const int*   prot_e = (const int*)  d_in[3];
    const float* phys   = (const float*)d_in[4];
    const float* W1     = (const float*)d_in[5];
    const float* b1     = (const float*)d_in[6];
    const float* W2     = (const float*)d_in[7];
    const float* b2     = (const float*)d_in[8];
    const float* Wfc    = (const float*)d_in[9];
    const float* bfc    = (const float*)d_in[10];
    float* out = (float*)d_out;

    int Nm = in_sizes[0], Em = in_sizes[1] / 2;
    int Np = in_sizes[2], Ep = in_sizes[3] / 2;
    int Ntot = Nm + Np, Etot = Em + Ep;

    int NBKT = CDIV(Ntot, 4096);
    int NBIN = CDIV(Etot, 2304);
    int per  = CDIV(Etot, NBIN);
    int M    = NBKT * NBIN;

    char* p = (char*)d_ws;
    auto alloc = [&](size_t bytes) -> char* {
        char* r = p;
        p += (bytes + 255) & ~(size_t)255;
        return r;
    };
    float*  agg2  = (float*) alloc((size_t)Ntot * 128 * 4);   // fallback only
    int*    sorted= (int*)   alloc((size_t)Etot * 4);         // fallback only
    int*    srcb  = (int*)   alloc((size_t)Etot * 4);
    int*    dstb  = (int*)   alloc((size_t)Etot * 4);
    int*    cmat  = (int*)   alloc((size_t)M * 4);
    int*    coff  = (int*)   alloc((size_t)M * 4);
    int*    tilesA= (int*)   alloc(4096);
    int*    tilesB= (int*)   alloc(4096);
    int*    hist  = (int*)   alloc((size_t)Ntot * 4);         // ---- memset region start
    float*  s_acc = (float*) alloc((size_t)Ntot * 4);
    float*  PM    = (float*) alloc((size_t)Ntot * 8);
    float*  pool  = (float*) alloc(256 * 4);                  // ---- memset region end
    int*    rowst = (int*)   alloc((size_t)Ntot * 4);         // fallback
    int*    cursor= (int*)   alloc((size_t)Ntot * 4);         // fallback
    float*  xi    = (float*) alloc((size_t)Ntot * 4);
    float2* si    = (float2*)alloc((size_t)Ntot * 8);
    float*  u     = (float*) alloc(128 * 4);
    float*  v     = (float*) alloc(128 * 4);
    int*    flags = (int*)   alloc(256);

    size_t zbytes = (char*)(pool + 256) - (char*)hist;
    hipMemsetAsync(hist, 0, zbytes, stream);                  // hist + s_acc + PM + pool

    int B   = CDIV(Ntot, 256);
    int B2  = CDIV(M, 256);
    const int WPB_A = 32, WPB_B = 32, WPB_C = 16;

    k_flag    <<<1, 128, 0, stream>>>(b1, flags);
    // ---- bin edges by dst bucket ----
    k_count   <<<NBIN, 256, 0, stream>>>(mol_e, prot_e, Em, Ep, Nm, per, NBIN, NBKT, cmat);
    k_scan_tile<<<B2, 256, 0, stream>>>(cmat, M, coff, tilesA);
    k_scan_sums<<<1, 1024, 0, stream>>>(tilesA, B2);
    k_scan_add <<<B2, 256, 0, stream>>>(coff, M, tilesA);
    k_binsort <<<NBIN, 256, 0, stream>>>(mol_e, prot_e, Em, Ep, Nm, per, NBIN, NBKT,
                                         coff, srcb, dstb);
    // ---- LDS-resident accumulations over binned edges ----
    k_accA<<<NBKT * WPB_A, 256, 0, stream>>>(dstb, coff, NBIN, NBKT, WPB_A, Etot, Ntot, hist);
    k_inv <<<B, 256, 0, stream>>>(hist, mol_x, prot_x, Nm, Ntot, xi);
    k_accB<<<NBKT * WPB_B, 256, 0, stream>>>(srcb, dstb, coff, xi,
                                             NBIN, NBKT, WPB_B, Etot, Ntot, s_acc);
    k_s   <<<B, 256, 0, stream>>>(hist, s_acc, xi, Ntot, si);
    k_accC<<<NBKT * WPB_C, 256, 0, stream>>>(srcb, dstb, coff, si,
                                             NBIN, NBKT, WPB_C, Etot, Ntot, PM, flags);
    // ---- fast-path epilogue (tile-transposed pooled eval, per branch) ----
    k_uv       <<<1, 128, 0, stream>>>(W1, W2, u, v, flags);
    {
        int gm = CDIV(CDIV(Nm, 128), 2);
        int gp = CDIV(CDIV(Np, 128), 2);
        k_pool_fact<<<gm, 256, 0, stream>>>(si, PM, u, v, b2, 0,  Nm, pool,       flags);
        k_pool_fact<<<gp, 256, 0, stream>>>(si, PM, u, v, b2, Nm, Np, pool + 128, flags);
    }
    // ---- fallback path (b1 != 0) ----
    k_scan_tileF<<<B, 256, 0, stream>>>(hist, Ntot, rowst, tilesB, flags);
    k_scan_sumsF<<<1, 1024, 0, stream>>>(tilesB, B, flags);
    k_scan_addF <<<B, 256, 0, stream>>>(rowst, Ntot, tilesB, cursor, flags);
    k_build     <<<CDIV(Etot, 256), 256, 0, stream>>>(mol_e, prot_e, Em, Ep, Nm,
                                                      cursor, sorted, flags);
    k_agg2      <<<4096, 256, 0, stream>>>(rowst, hist, si, sorted, W1, b1, Ntot, agg2, flags);
    k_mm_pool   <<<CDIV(Nm, 64), 256, 0, stream>>>(agg2, W2, b2, Nm, pool, flags);
    k_mm_pool   <<<CDIV(Np, 64), 256, 0, stream>>>(agg2 + (size_t)Nm * 128, W2, b2,
                                                   Np, pool + 128, flags);

    k_final<<<1, 256, 0, stream>>>(pool, phys, Wfc, bfc, out);
}

// Round 9
// 171.252 us; speedup vs baseline: 14.5929x; 1.0051x over previous
//
#include <hip/hip_runtime.h>

#define CDIV(a,b) (((a)+(b)-1)/(b))

// Combined node ids: mol [0,Nm), prot [Nm,Nm+Np).  Bucket = node >> 12 (4096 nodes/bkt,
// NBKT <= 64; node ids < 2^18 so (dlo<<18)|src packs an edge into one int).
// k_count: 37 per-bucket totals.  k_bin: dynamic range reservation per block (LDS
// histogram + 1 global atomic/bucket) + in-LDS grouping + coalesced packed writeout.
// k_accA/B/C: LDS-resident per-bucket accumulation (deg, s_acc, PM) + coalesced flush.
// Fast path (b1==0): relu bilinear sign-split -> rank-2 factorized layer 2.
// Fallback (b1!=0): CSR pipeline, guarded by flags[0], grid-capped.

// ---------------- flag + u/v precompute (1 block, 128 threads) ----------------
__global__ void k_flaguv(const float* __restrict__ b1, const float* __restrict__ W1,
                         const float* __restrict__ W2, float* __restrict__ u,
                         float* __restrict__ v, int* __restrict__ flags) {
    __shared__ int nz;
    int t = threadIdx.x;                       // 128 threads
    if (t == 0) nz = 0;
    __syncthreads();
    if (b1[t] != 0.f) atomicOr(&nz, 1);
    float au = 0.f, av = 0.f;
    for (int j = 0; j < 128; ++j) {
        float w = W1[j], w2 = W2[j * 128 + t];
        au = fmaf(fmaxf(w, 0.f), w2, au);
        av = fmaf(fmaxf(-w, 0.f), w2, av);
    }
    u[t] = au;
    v[t] = av;
    __syncthreads();
    if (t == 0) flags[0] = nz;
}

// ---------------- bucket totals ----------------
__global__ __launch_bounds__(256) void k_count(
        const int* __restrict__ me, const int* __restrict__ pe,
        int Em, int Ep, int Nm, int per, int NBKT, int* __restrict__ btot) {
    __shared__ int cnt[64];
    int t = threadIdx.x;
    int Etot = Em + Ep;
    int e0 = blockIdx.x * per, e1 = min(e0 + per, Etot);
    if (t < 64) cnt[t] = 0;
    __syncthreads();
    for (int e = e0 + t; e < e1; e += 256) {
        int d = (e < Em) ? me[Em + e] : (pe[Ep + (e - Em)] + Nm);
        atomicAdd(&cnt[d >> 12], 1);
    }
    __syncthreads();
    if (t < NBKT && cnt[t]) atomicAdd(&btot[t], cnt[t]);
}

// ---------------- dynamic-reservation binning (packed writeout) ----------------
#define BINCAP 4096
__global__ __launch_bounds__(256) void k_bin(
        const int* __restrict__ me, const int* __restrict__ pe,
        int Em, int Ep, int Nm, int per, int NBKT,
        const int* __restrict__ btot, int* __restrict__ gcur, int* __restrict__ pkb) {
    __shared__ int lpk[BINCAP];
    __shared__ unsigned char lbkt[BINCAP];
    __shared__ int cnt[64], cst[64], cur[64], wbase[64], bb[64];
    int t = threadIdx.x;
    int Etot = Em + Ep;
    int e0 = blockIdx.x * per, e1 = min(e0 + per, Etot);
    int ne = max(e1 - e0, 0);
    if (t < 64) cnt[t] = 0;
    __syncthreads();
    for (int e = e0 + t; e < e1; e += 256) {
        int d = (e < Em) ? me[Em + e] : (pe[Ep + (e - Em)] + Nm);
        atomicAdd(&cnt[d >> 12], 1);
    }
    __syncthreads();
    if (t == 0) {
        int run = 0, runb = 0;
        for (int b = 0; b < NBKT; ++b) {
            cst[b] = run; cur[b] = run; run += cnt[b];
            bb[b] = runb; runb += btot[b];
        }
    }
    __syncthreads();
    if (t < NBKT) wbase[t] = bb[t] + (cnt[t] ? atomicAdd(&gcur[t], cnt[t]) : 0);
    __syncthreads();
    for (int e = e0 + t; e < e1; e += 256) {
        int s, d;
        if (e < Em) { s = me[e];            d = me[Em + e]; }
        else        { int ee = e - Em; s = pe[ee] + Nm; d = pe[Ep + ee] + Nm; }
        int b = d >> 12;
        int p = atomicAdd(&cur[b], 1);
        lpk[p]  = ((d & 4095) << 18) | s;      // node ids < 2^18
        lbkt[p] = (unsigned char)b;
    }
    __syncthreads();
    for (int i = t; i < ne; i += 256) {
        int b = lbkt[i];
        pkb[wbase[b] + (i - cst[b])] = lpk[i];
    }
}

// ---------------- accumulate A: degree histogram ----------------
__global__ __launch_bounds__(256) void k_accA(
        const int* __restrict__ pkb, const int* __restrict__ btot,
        int NBKT, int WPB, int Ntot, int* __restrict__ hist) {
    __shared__ int h[4096];
    __shared__ int sbs, sbe;
    int b = blockIdx.x / WPB, sl = blockIdx.x % WPB, t = threadIdx.x;
    if (t == 0) {
        int run = 0;
        for (int i = 0; i < b; ++i) run += btot[i];
        sbs = run; sbe = run + btot[b];
    }
    for (int k = t; k < 4096; k += 256) h[k] = 0;
    __syncthreads();
    for (int i = sbs + sl * 256 + t; i < sbe; i += WPB * 256)
        atomicAdd(&h[pkb[i] >> 18], 1);
    __syncthreads();
    for (int k = t; k < 4096; k += 256) {
        int v = h[k];
        int node = (b << 12) + k;
        if (v && node < Ntot) atomicAdd(&hist[node], v);
    }
}

// ---------------- per-node: xi = x * rsqrt(deg+1) ----------------
__global__ void k_inv(const int* __restrict__ hist,
                      const float* __restrict__ mx, const float* __restrict__ px,
                      int Nm, int Ntot, float* __restrict__ xi) {
    int g = blockIdx.x * 256 + threadIdx.x;
    if (g < Ntot) {
        float x = (g < Nm) ? mx[g] : px[g - Nm];
        xi[g] = x * rsqrtf((float)(hist[g] + 1));
    }
}

// ---------------- accumulate B: s_acc[d] += xi[src] ----------------
__global__ __launch_bounds__(256) void k_accB(
        const int* __restrict__ pkb, const int* __restrict__ btot,
        const float* __restrict__ xi, int NBKT, int WPB, int Ntot,
        float* __restrict__ s_acc) {
    __shared__ float acc[4096];
    __shared__ int sbs, sbe;
    int b = blockIdx.x / WPB, sl = blockIdx.x % WPB, t = threadIdx.x;
    if (t == 0) {
        int run = 0;
        for (int i = 0; i < b; ++i) run += btot[i];
        sbs = run; sbe = run + btot[b];
    }
    for (int k = t; k < 4096; k += 256) acc[k] = 0.f;
    __syncthreads();
    for (int i = sbs + sl * 256 + t; i < sbe; i += WPB * 256) {
        int pk = pkb[i];
        atomicAdd(&acc[pk >> 18], xi[pk & 0x3FFFF]);
    }
    __syncthreads();
    for (int k = t; k < 4096; k += 256) {
        float v = acc[k];
        int node = (b << 12) + k;
        if (v != 0.f && node < Ntot) atomicAdd(&s_acc[node], v);
    }
}

// ---------------- layer-1 finalize: si[d] = (inv*(s_acc+xi), inv) ----------------
__global__ void k_s(const int* __restrict__ hist, const float* __restrict__ s_acc,
                    const float* __restrict__ xi, int Ntot, float2* __restrict__ si) {
    int i = blockIdx.x * 256 + threadIdx.x;
    if (i >= Ntot) return;
    float iv = rsqrtf((float)(hist[i] + 1));
    si[i] = make_float2(iv * (s_acc[i] + xi[i]), iv);
}

// ---------------- accumulate C (fast only): P/M sign-split sums ----------------
__global__ __launch_bounds__(256) void k_accC(
        const int* __restrict__ pkb, const int* __restrict__ btot,
        const float2* __restrict__ si, int NBKT, int WPB, int Ntot,
        float* __restrict__ PM, const int* __restrict__ flags) {
    if (flags[0]) return;
    __shared__ float pm[8192];
    __shared__ int sbs, sbe;
    int b = blockIdx.x / WPB, sl = blockIdx.x % WPB, t = threadIdx.x;
    if (t == 0) {
        int run = 0;
        for (int i = 0; i < b; ++i) run += btot[i];
        sbs = run; sbe = run + btot[b];
    }
    for (int k = t; k < 8192; k += 256) pm[k] = 0.f;
    __syncthreads();
    for (int i = sbs + sl * 256 + t; i < sbe; i += WPB * 256) {
        int pk = pkb[i];
        float2 q = si[pk & 0x3FFFF];
        float val = q.y * q.x;
        int lo = (pk >> 18) * 2;
        if (val > 0.f)      atomicAdd(&pm[lo],     val);
        else if (val < 0.f) atomicAdd(&pm[lo + 1], -val);
    }
    __syncthreads();
    for (int k = t; k < 8192; k += 256) {
        float v = pm[k];
        int node = (b << 12) + (k >> 1);
        if (v != 0.f && node < Ntot) atomicAdd(&PM[2 * node + (k & 1)], v);
    }
}

// ---------------- fast: pooled output, tile-transposed, mol+prot in ONE launch -------
__global__ __launch_bounds__(256) void k_pool_fact(
        const float2* __restrict__ si, const float* __restrict__ PM,
        const float* __restrict__ u, const float* __restrict__ v,
        const float* __restrict__ b2, int Nm, int Np, int gm, int gp,
        float* __restrict__ pool, const int* __restrict__ flags) {
    if (flags[0]) return;
    __shared__ float sA[2][128], sB[2][128], sR[2][128];
    int t = threadIdx.x;
    int k = t & 127;
    int grp = t >> 7;
    int blk = blockIdx.x;
    int base, cnt, gstart, gsize;
    float* poolOut;
    if (blk < gm) { base = 0;  cnt = Nm; gstart = blk;      gsize = gm; poolOut = pool; }
    else          { base = Nm; cnt = Np; gstart = blk - gm; gsize = gp; poolOut = pool + 128; }
    float uk = u[k], vk = v[k], bk = b2[k];
    float acc = 0.f;
    int ntile = (cnt + 127) >> 7;
    for (int tb = gstart * 2; tb < ntile; tb += gsize * 2) {
        int tile = tb + grp;
        int d0 = base + tile * 128;
        int nn = (tile < ntile) ? min(128, base + cnt - d0) : 0;
        float A = 0.f, B = 0.f;
        if (k < nn) {
            float2 q  = si[d0 + k];
            float2 pm = *(const float2*)&PM[2 * (d0 + k)];
            float iv = q.y;
            A = iv * fmaf(iv, fmaxf(q.x, 0.f), pm.x);
            B = iv * fmaf(iv, fmaxf(-q.x, 0.f), pm.y);
        }
        __syncthreads();
        sA[grp][k] = A;
        sB[grp][k] = B;
        __syncthreads();
        #pragma unroll 8
        for (int i = 0; i < nn; ++i)
            acc += fmaxf(fmaf(sA[grp][i], uk, fmaf(sB[grp][i], vk, bk)), 0.f);
    }
    __syncthreads();
    sR[grp][k] = acc;
    __syncthreads();
    if (t < 128) atomicAdd(&poolOut[t], sR[0][t] + sR[1][t]);
}

// ================= fallback path (b1 != 0), guarded, grid-capped =================

__global__ void k_scan_tileF(const int* __restrict__ in, int N,
                             int* __restrict__ out, int* __restrict__ tilesums,
                             const int* __restrict__ flags) {
    if (!flags[0]) return;
    __shared__ int sm[256];
    int t = threadIdx.x;
    int g = blockIdx.x * 256 + t;
    int v = (g < N) ? in[g] : 0;
    sm[t] = v;
    __syncthreads();
    for (int off = 1; off < 256; off <<= 1) {
        int x = sm[t];
        int y = (t >= off) ? sm[t - off] : 0;
        __syncthreads();
        sm[t] = x + y;
        __syncthreads();
    }
    int incl = sm[t];
    if (g < N) out[g] = incl - v;
    if (t == 255) tilesums[blockIdx.x] = incl;
}

__global__ void k_scan_sumsF(int* __restrict__ sums, int B, const int* __restrict__ flags) {
    if (!flags[0]) return;
    __shared__ int sm[1024];
    int t = threadIdx.x;
    int v = (t < B) ? sums[t] : 0;
    sm[t] = v;
    __syncthreads();
    for (int off = 1; off < 1024; off <<= 1) {
        int x = sm[t];
        int y = (t >= off) ? sm[t - off] : 0;
        __syncthreads();
        sm[t] = x + y;
        __syncthreads();
    }
    if (t < B) sums[t] = sm[t] - v;
}

__global__ void k_scan_addF(int* __restrict__ rowst, int Ntot,
                            const int* __restrict__ sums, int* __restrict__ cursor,
                            const int* __restrict__ flags) {
    if (!flags[0]) return;
    int g = blockIdx.x * 256 + threadIdx.x;
    if (g < Ntot) {
        int v = rowst[g] + sums[blockIdx.x];
        rowst[g] = v;
        cursor[g] = v;
    }
}

__global__ void k_build(const int* __restrict__ me, const int* __restrict__ pe,
                        int Em, int Ep, int Nm,
                        int* __restrict__ cursor, int* __restrict__ sorted,
                        const int* __restrict__ flags) {
    if (!flags[0]) return;
    int Etot = Em + Ep;
    for (int e = blockIdx.x * 256 + threadIdx.x; e < Etot; e += gridDim.x * 256) {
        int s, d;
        if (e < Em) { s = me[e];            d = me[Em + e]; }
        else        { int ee = e - Em; s = pe[ee] + Nm; d = pe[Ep + ee] + Nm; }
        int p = atomicAdd(&cursor[d], 1);
        sorted[p] = s;
    }
}

__global__ __launch_bounds__(256) void k_agg2(
        const int* __restrict__ rowst, const int* __restrict__ hist,
        const float2* __restrict__ si, const int* __restrict__ sorted,
        const float* __restrict__ W1, const float* __restrict__ b1,
        int Ntot, float* __restrict__ agg2, const int* __restrict__ flags) {
    if (!flags[0]) return;
    int lane = threadIdx.x & 63;
    int wv   = (blockIdx.x * 256 + threadIdx.x) >> 6;
    int nW   = gridDim.x * 4;
    float wa = W1[lane],  wb  = W1[lane + 64];
    float ba = b1[lane],  bbv = b1[lane + 64];
    for (int d = wv; d < Ntot; d += nW) {
        int st  = rowst[d];
        int cnt = hist[d];
        float aa = 0.f, ab = 0.f;
        for (int b0 = 0; b0 < cnt; b0 += 64) {
            int take = cnt - b0; if (take > 64) take = 64;
            int l = (lane < take) ? lane : 0;
            int idx = sorted[st + b0 + l];
            float2 sv = si[idx];
            for (int i = 0; i < take; ++i) {
                float s_i = __shfl(sv.x, i);
                float v_i = __shfl(sv.y, i);
                aa = fmaf(v_i, fmaxf(fmaf(s_i, wa, ba ), 0.f), aa);
                ab = fmaf(v_i, fmaxf(fmaf(s_i, wb, bbv), 0.f), ab);
            }
        }
        float2 ps = si[d];
        float oa = fmaxf(fmaf(ps.x, wa, ba ), 0.f);
        float ob = fmaxf(fmaf(ps.x, wb, bbv), 0.f);
        agg2[(size_t)d * 128 + lane]      = ps.y * (aa + ps.y * oa);
        agg2[(size_t)d * 128 + 64 + lane] = ps.y * (ab + ps.y * ob);
    }
}

__global__ __launch_bounds__(256, 2) void k_mm_pool(
        const float* __restrict__ agg2, const float* __restrict__ W2,
        const float* __restrict__ b2, int N, float* __restrict__ pool,
        const int* __restrict__ flags) {
    if (!flags[0]) return;
    __shared__ float sW[128 * 128];
    __shared__ float sR[8 * 128];
    int t = threadIdx.x;
    {
        const float4* srcp = (const float4*)W2;
        float4* dstp = (float4*)sW;
        for (int i = t; i < 128 * 128 / 4; i += 256) dstp[i] = srcp[i];
    }
    __syncthreads();

    int jg = t & 31;
    int rg = t >> 5;
    int j0 = jg * 4;
    const float4 bbv = *(const float4*)&b2[j0];
    float4 pA = make_float4(0.f, 0.f, 0.f, 0.f);

    for (int tile = blockIdx.x; tile * 64 < N; tile += gridDim.x) {
        int r0 = tile * 64 + rg * 8;
        const float* p0 = agg2 + (size_t)min(r0 + 0, N - 1) * 128;
        const float* p1 = agg2 + (size_t)min(r0 + 1, N - 1) * 128;
        const float* p2 = agg2 + (size_t)min(r0 + 2, N - 1) * 128;
        const float* p3 = agg2 + (size_t)min(r0 + 3, N - 1) * 128;
        const float* p4 = agg2 + (size_t)min(r0 + 4, N - 1) * 128;
        const float* p5 = agg2 + (size_t)min(r0 + 5, N - 1) * 128;
        const float* p6 = agg2 + (size_t)min(r0 + 6, N - 1) * 128;
        const float* p7 = agg2 + (size_t)min(r0 + 7, N - 1) * 128;

        float4 acc0 = bbv, acc1 = bbv, acc2 = bbv, acc3 = bbv;
        float4 acc4 = bbv, acc5 = bbv, acc6 = bbv, acc7 = bbv;
        float4 w0, w1, w2, w3;
        float4 xA0, xA1, xA2, xA3, xA4, xA5, xA6, xA7;
        float4 xB0, xB1, xB2, xB3, xB4, xB5, xB6, xB7;

#define LOADA(X, kk) \
        X##0 = *(const float4*)(p0 + (kk)); X##1 = *(const float4*)(p1 + (kk)); \
        X##2 = *(const float4*)(p2 + (kk)); X##3 = *(const float4*)(p3 + (kk)); \
        X##4 = *(const float4*)(p4 + (kk)); X##5 = *(const float4*)(p5 + (kk)); \
        X##6 = *(const float4*)(p6 + (kk)); X##7 = *(const float4*)(p7 + (kk));

#define WLOAD(kk) \
        w0 = *(const float4*)&sW[((kk) + 0) * 128 + j0]; \
        w1 = *(const float4*)&sW[((kk) + 1) * 128 + j0]; \
        w2 = *(const float4*)&sW[((kk) + 2) * 128 + j0]; \
        w3 = *(const float4*)&sW[((kk) + 3) * 128 + j0];

#define FMAROW(acc, av) \
        acc.x = fmaf(av.x, w0.x, acc.x); acc.y = fmaf(av.x, w0.y, acc.y); \
        acc.z = fmaf(av.x, w0.z, acc.z); acc.w = fmaf(av.x, w0.w, acc.w); \
        acc.x = fmaf(av.y, w1.x, acc.x); acc.y = fmaf(av.y, w1.y, acc.y); \
        acc.z = fmaf(av.y, w1.z, acc.z); acc.w = fmaf(av.y, w1.w, acc.w); \
        acc.x = fmaf(av.z, w2.x, acc.x); acc.y = fmaf(av.z, w2.y, acc.y); \
        acc.z = fmaf(av.z, w2.z, acc.z); acc.w = fmaf(av.z, w2.w, acc.w); \
        acc.x = fmaf(av.w, w3.x, acc.x); acc.y = fmaf(av.w, w3.y, acc.y); \
        acc.z = fmaf(av.w, w3.z, acc.z); acc.w = fmaf(av.w, w3.w, acc.w);

#define FMALL(X) \
        FMAROW(acc0, X##0) FMAROW(acc1, X##1) FMAROW(acc2, X##2) FMAROW(acc3, X##3) \
        FMAROW(acc4, X##4) FMAROW(acc5, X##5) FMAROW(acc6, X##6) FMAROW(acc7, X##7)

        LOADA(xA, 0)
        for (int k = 0; k < 128; k += 8) {
            LOADA(xB, k + 4)
            WLOAD(k)
            FMALL(xA)
            if (k + 8 < 128) { LOADA(xA, k + 8) }
            WLOAD(k + 4)
            FMALL(xB)
        }
#undef LOADA
#undef WLOAD
#undef FMAROW
#undef FMALL

#define POOLROW(i, acc) \
        if (r0 + i < N) { pA.x += fmaxf(acc.x, 0.f); pA.y += fmaxf(acc.y, 0.f); \
                          pA.z += fmaxf(acc.z, 0.f); pA.w += fmaxf(acc.w, 0.f); }
        POOLROW(0, acc0) POOLROW(1, acc1) POOLROW(2, acc2) POOLROW(3, acc3)
        POOLROW(4, acc4) POOLROW(5, acc5) POOLROW(6, acc6) POOLROW(7, acc7)
#undef POOLROW
    }

    *(float4*)&sR[rg * 128 + j0] = pA;
    __syncthreads();
    if (t < 128) {
        float s = 0.f;
        #pragma unroll
        for (int r = 0; r < 8; ++r) s += sR[r * 128 + t];
        atomicAdd(&pool[t], s);
    }
}

// ---------------- final 257-dim dot ----------------
__global__ void k_final(const float* __restrict__ pool, const float* __restrict__ phys,
                        const float* __restrict__ Wfc, const float* __restrict__ bfc,
                        float* __restrict__ out) {
    __shared__ float sm[256];
    int t = threadIdx.x;
    float acc = pool[t] * Wfc[t];
    if (t == 0) acc += phys[0] * Wfc[256] + bfc[0];
    sm[t] = acc;
    __syncthreads();
    for (int off = 128; off > 0; off >>= 1) {
        if (t < off) sm[t] += sm[t + off];
        __syncthreads();
    }
    if (t == 0) out[0] = sm[0];
}

extern "C" void kernel_launch(void* const* d_in, const int* in_sizes, int n_in,
                              void* d_out, int out_size, void* d_ws, size_t ws_size,
                              hipStream_t stream) {
    const float* mol_x  = (const float*)d_in[0];
    const int*   mol_e  = (const int*)  d_in[1];
    const float* prot_x = (const float*)d_in[2];
    const int*   prot_e = (const int*)  d_in[3];
    const float* phys   = (const float*)d_in[4];
    const float* W1     = (const float*)d_in[5];
    const float* b1     = (const float*)d_in[6];
    const float* W2     = (const float*)d_in[7];
    const float* b2     = (const float*)d_in[8];
    const float* Wfc    = (const float*)d_in[9];
    const float* bfc    = (const float*)d_in[10];
    float* out = (float*)d_out;

    int Nm = in_sizes[0], Em = in_sizes[1] / 2;
    int Np = in_sizes[2], Ep = in_sizes[3] / 2;
    int Ntot = Nm + Np, Etot = Em + Ep;

    int NBKT = CDIV(Ntot, 4096);               // <= 64 (node ids < 2^18 for packing)
    int NBIN = CDIV(Etot, BINCAP);
    int per  = CDIV(Etot, NBIN);               // <= BINCAP

    char* p = (char*)d_ws;
    auto alloc = [&](size_t bytes) -> char* {
        char* r = p;
        p += (bytes + 255) & ~(size_t)255;
        return r;
    };
    float*  agg2  = (float*) alloc((size_t)Ntot * 128 * 4);   // fallback only
    int*    sorted= (int*)   alloc((size_t)Etot * 4);         // fallback only
    int*    pkb   = (int*)   alloc((size_t)Etot * 4);         // packed binned edges
    int*    hist  = (int*)   alloc((size_t)Ntot * 4);         // ---- memset region start
    float*  s_acc = (float*) alloc((size_t)Ntot * 4);
    float*  PM    = (float*) alloc((size_t)Ntot * 8);
    float*  pool  = (float*) alloc(256 * 4);
    int*    btot  = (int*)   alloc(64 * 4);
    int*    gcur  = (int*)   alloc(64 * 4);                   // ---- memset region end
    int*    rowst = (int*)   alloc((size_t)Ntot * 4);         // fallback
    int*    cursor= (int*)   alloc((size_t)Ntot * 4);         // fallback
    int*    tilesB= (int*)   alloc(4096);                     // fallback
    float*  xi    = (float*) alloc((size_t)Ntot * 4);
    float2* si    = (float2*)alloc((size_t)Ntot * 8);
    float*  u     = (float*) alloc(128 * 4);
    float*  v     = (float*) alloc(128 * 4);
    int*    flags = (int*)   alloc(256);

    size_t zbytes = (char*)(gcur + 64) - (char*)hist;
    hipMemsetAsync(hist, 0, zbytes, stream);    // hist + s_acc + PM + pool + btot + gcur

    int B = CDIV(Ntot, 256);
    const int WPB_A = 32, WPB_B = 32, WPB_C = 16;

    k_flaguv<<<1, 128, 0, stream>>>(b1, W1, W2, u, v, flags);
    // ---- bin edges by dst bucket (2 launches, dynamic reservation, packed) ----
    k_count<<<NBIN, 256, 0, stream>>>(mol_e, prot_e, Em, Ep, Nm, per, NBKT, btot);
    k_bin  <<<NBIN, 256, 0, stream>>>(mol_e, prot_e, Em, Ep, Nm, per, NBKT,
                                      btot, gcur, pkb);
    // ---- LDS-resident accumulations over binned packed edges ----
    k_accA<<<NBKT * WPB_A, 256, 0, stream>>>(pkb, btot, NBKT, WPB_A, Ntot, hist);
    k_inv <<<B, 256, 0, stream>>>(hist, mol_x, prot_x, Nm, Ntot, xi);
    k_accB<<<NBKT * WPB_B, 256, 0, stream>>>(pkb, btot, xi, NBKT, WPB_B, Ntot, s_acc);
    k_s   <<<B, 256, 0, stream>>>(hist, s_acc, xi, Ntot, si);
    k_accC<<<NBKT * WPB_C, 256, 0, stream>>>(pkb, btot, si, NBKT, WPB_C, Ntot, PM, flags);
    // ---- fast-path epilogue (single merged launch) ----
    {
        int gm = CDIV(CDIV(Nm, 128), 2);
        int gp = CDIV(CDIV(Np, 128), 2);
        k_pool_fact<<<gm + gp, 256, 0, stream>>>(si, PM, u, v, b2, Nm, Np, gm, gp,
                                                 pool, flags);
    }
    // ---- fallback path (b1 != 0), grid-capped ----
    k_scan_tileF<<<B, 256, 0, stream>>>(hist, Ntot, rowst, tilesB, flags);
    k_scan_sumsF<<<1, 1024, 0, stream>>>(tilesB, B, flags);
    k_scan_addF <<<B, 256, 0, stream>>>(rowst, Ntot, tilesB, cursor, flags);
    k_build     <<<2048, 256, 0, stream>>>(mol_e, prot_e, Em, Ep, Nm,
                                           cursor, sorted, flags);
    k_agg2      <<<2048, 256, 0, stream>>>(rowst, hist, si, sorted, W1, b1, Ntot,
                                           agg2, flags);
    k_mm_pool   <<<512, 256, 0, stream>>>(agg2, W2, b2, Nm, pool, flags);
    k_mm_pool   <<<512, 256, 0, stream>>>(agg2 + (size_t)Nm * 128, W2, b2,
                                          Np, pool + 128, flags);

    k_final<<<1, 256, 0, stream>>>(pool, phys, Wfc, bfc, out);
}